// Round 1
// baseline (1454.056 us; speedup 1.0000x reference)
//
#include <hip/hip_runtime.h>
#include <math.h>

#define B_ 32
#define N_ 1024
#define F_ 64
#define P_ 8
#define n_ 128
#define m_ 256
#define e_ 1024
#define EF_ 8
#define T_ 16
#define H_ 128
#define W_ 8
#define G_ 128
#define R_ 256
#define L2_ 128

__device__ __forceinline__ float leakyf(float z, float s) { return z >= 0.f ? z : s * z; }

// 64-col f32 LDS tile with bank-conflict-free swizzle: col4 ^= (row>>3)&15
__device__ __forceinline__ int swz64(int r, int c) {
    return r * 64 + ((((c >> 2) ^ ((r >> 3) & 15)) << 2) | (c & 3));
}
__device__ __forceinline__ float4 ld64(const float* lds, int r, int c4) {
    return *reinterpret_cast<const float4*>(lds + r * 64 + ((c4 ^ ((r >> 3) & 15)) << 2));
}

// ---------------- K1: rx[b,p,e,f] = sum_m rinc[p,e,m] * x[b, nbr[p,m], f] ----------------
__global__ __launch_bounds__(256) void k_rx(const float* __restrict__ x,
                                            const float* __restrict__ rinc,
                                            const int* __restrict__ nbr,
                                            float* __restrict__ rx) {
    const int et = blockIdx.x;   // e-tile (64)
    const int p  = blockIdx.y;
    const int b  = blockIdx.z;
    const int t  = threadIdx.x;
    const int tf = t & 15;       // f_sub = tf*4
    const int te = t >> 4;       // e_sub = te*4
    __shared__ float xn[64 * 64];  // [m-chunk][f]  K-major
    __shared__ float rc[64 * 64];  // [ee][m-chunk] swizzled

    float acc[4][4];
#pragma unroll
    for (int i = 0; i < 4; i++)
#pragma unroll
        for (int j = 0; j < 4; j++) acc[i][j] = 0.f;

    const int e0 = et * 64;
    for (int c = 0; c < 4; c++) {
        const int m0 = c * 64;
        __syncthreads();
        for (int idx = t; idx < 4096; idx += 256) {
            int kl = idx >> 6, f = idx & 63;
            int row = nbr[p * m_ + m0 + kl];
            xn[kl * 64 + f] = x[(size_t)(b * N_ + row) * F_ + f];
        }
        for (int idx = t; idx < 4096; idx += 256) {
            int ee = idx >> 6, kk = idx & 63;
            rc[swz64(ee, kk)] = rinc[(size_t)(p * e_ + e0 + ee) * m_ + m0 + kk];
        }
        __syncthreads();
#pragma unroll 4
        for (int k4 = 0; k4 < 16; k4++) {
            float4 rv[4], xv[4];
#pragma unroll
            for (int i = 0; i < 4; i++) rv[i] = ld64(rc, te * 4 + i, k4);
#pragma unroll
            for (int j = 0; j < 4; j++)
                xv[j] = *reinterpret_cast<const float4*>(xn + (k4 * 4 + j) * 64 + tf * 4);
#pragma unroll
            for (int i = 0; i < 4; i++) {
                const float* rvp = reinterpret_cast<const float*>(&rv[i]);
#pragma unroll
                for (int j = 0; j < 4; j++) {
                    float a = rvp[j];
                    acc[i][0] += a * xv[j].x;
                    acc[i][1] += a * xv[j].y;
                    acc[i][2] += a * xv[j].z;
                    acc[i][3] += a * xv[j].w;
                }
            }
        }
    }
#pragma unroll
    for (int i = 0; i < 4; i++) {
        float4 v = make_float4(acc[i][0], acc[i][1], acc[i][2], acc[i][3]);
        size_t off = ((size_t)(b * P_ + p) * e_ + e0 + te * 4 + i) * F_ + tf * 4;
        *reinterpret_cast<float4*>(rx + off) = v;
    }
}

// ---------------- K2: u[b,p,n,h] = sum_f k3_w[p,h,f] * x[b, nodes[p,n], f] ----------------
__global__ __launch_bounds__(256) void k_u(const float* __restrict__ x,
                                           const float* __restrict__ k3w,
                                           const int* __restrict__ nodes,
                                           float* __restrict__ u) {
    const int p = blockIdx.x, b = blockIdx.y;
    const int t = threadIdx.x;
    const int th = t & 15;  // h_sub = th*8
    const int tn = t >> 4;  // n_sub = tn*8
    __shared__ float xg[128 * 64];  // [nn][f] swizzled
    __shared__ float kw[128 * 64];  // [h][f]  swizzled
    for (int idx = t; idx < 8192; idx += 256) {
        int r = idx >> 6, f = idx & 63;
        int row = nodes[p * n_ + r];
        xg[swz64(r, f)] = x[(size_t)(b * N_ + row) * F_ + f];
        kw[swz64(r, f)] = k3w[(size_t)(p * H_ + r) * F_ + f];
    }
    __syncthreads();
    float acc[8][8];
#pragma unroll
    for (int i = 0; i < 8; i++)
#pragma unroll
        for (int j = 0; j < 8; j++) acc[i][j] = 0.f;
#pragma unroll 2
    for (int k4 = 0; k4 < 16; k4++) {
        float4 xv[8];
#pragma unroll
        for (int i = 0; i < 8; i++) xv[i] = ld64(xg, tn * 8 + i, k4);
#pragma unroll
        for (int j = 0; j < 8; j++) {
            float4 kv = ld64(kw, th * 8 + j, k4);
#pragma unroll
            for (int i = 0; i < 8; i++) {
                acc[i][j] += xv[i].x * kv.x + xv[i].y * kv.y + xv[i].z * kv.z + xv[i].w * kv.w;
            }
        }
    }
#pragma unroll
    for (int i = 0; i < 8; i++) {
        size_t base = ((size_t)(b * P_ + p) * n_ + tn * 8 + i) * H_ + th * 8;
        *reinterpret_cast<float4*>(u + base) = make_float4(acc[i][0], acc[i][1], acc[i][2], acc[i][3]);
        *reinterpret_cast<float4*>(u + base + 4) = make_float4(acc[i][4], acc[i][5], acc[i][6], acc[i][7]);
    }
}

// ---------------- K3: kernel[b,p,e,w] via fused K=217 GEMM + leaky + k5 contraction ----------------
__global__ __launch_bounds__(256) void k_kern(const float* __restrict__ linc,
                                              const float* __restrict__ u,
                                              const float* __restrict__ rx,
                                              const float* __restrict__ k4w,
                                              const float* __restrict__ ef,
                                              const float* __restrict__ k1w,
                                              const float* __restrict__ k1b,
                                              const float* __restrict__ tin,
                                              const float* __restrict__ k2w,
                                              const float* __restrict__ k5w,
                                              const float* __restrict__ k5b,
                                              float* __restrict__ kern) {
    const int et = blockIdx.x;  // e-tile (64)
    const int p = blockIdx.y;
    const int b = blockIdx.z;
    const int t = threadIdx.x;
    const int tx = t & 15;   // e_sub = tx*4
    const int ty = t >> 4;   // h_sub = ty*8
    __shared__ float al[64 * 64];    // [kk][ee] K-major
    __shared__ float bl[64 * 128];   // [kk][h]  K-major (reused as reduction buf)
    __shared__ float k5l[8 * 128];

    for (int idx = t; idx < 1024; idx += 256) k5l[idx] = k5w[p * W_ * H_ + idx];

    float acc[4][8];
#pragma unroll
    for (int i = 0; i < 4; i++)
#pragma unroll
        for (int j = 0; j < 8; j++) acc[i][j] = 0.f;

    const int e0 = et * 64;
    for (int c = 0; c < 4; c++) {
        const int k0 = c * 64;
        __syncthreads();
        for (int idx = t; idx < 4096; idx += 256) {
            int kl = idx >> 6, ee = idx & 63;
            int kg = k0 + kl;
            float v;
            if (kg < 128)      v = linc[(size_t)(p * n_ + kg) * e_ + e0 + ee];
            else if (kg < 192) v = rx[((size_t)(b * P_ + p) * e_ + e0 + ee) * F_ + (kg - 128)];
            else if (kg < 200) v = ef[(size_t)(p * e_ + e0 + ee) * (EF_ + 1) + (kg - 192)];
            else if (kg < 216) v = tin[b * T_ + (kg - 200)];
            else if (kg == 216) v = 1.0f;
            else               v = 0.f;
            al[kl * 64 + ee] = v;
        }
        for (int idx = t; idx < 8192; idx += 256) {
            int kl = idx >> 7, h = idx & 127;
            int kg = k0 + kl;
            float v;
            if (kg < 128)      v = u[((size_t)(b * P_ + p) * n_ + kg) * H_ + h];
            else if (kg < 192) v = k4w[(size_t)(p * H_ + h) * F_ + (kg - 128)];
            else if (kg < 200) v = k1w[(size_t)(p * H_ + h) * EF_ + (kg - 192)];
            else if (kg < 216) v = k2w[(size_t)(p * H_ + h) * T_ + (kg - 200)];
            else if (kg == 216) v = k1b[p * H_ + h];
            else               v = 0.f;
            bl[kl * 128 + h] = v;
        }
        __syncthreads();
#pragma unroll 4
        for (int kk = 0; kk < 64; kk++) {
            float4 a4 = *reinterpret_cast<const float4*>(al + kk * 64 + tx * 4);
            float4 b4a = *reinterpret_cast<const float4*>(bl + kk * 128 + ty * 8);
            float4 b4b = *reinterpret_cast<const float4*>(bl + kk * 128 + ty * 8 + 4);
            const float* ap = reinterpret_cast<const float*>(&a4);
            const float* bpa = reinterpret_cast<const float*>(&b4a);
            const float* bpb = reinterpret_cast<const float*>(&b4b);
#pragma unroll
            for (int i = 0; i < 4; i++) {
#pragma unroll
                for (int j = 0; j < 4; j++) {
                    acc[i][j] += ap[i] * bpa[j];
                    acc[i][j + 4] += ap[i] * bpb[j];
                }
            }
        }
    }
    // epilogue: leaky(k), contract with k5_w over this thread's 8 h's
    float part[4][8];
#pragma unroll
    for (int i = 0; i < 4; i++) {
#pragma unroll
        for (int w = 0; w < 8; w++) {
            float s = 0.f;
#pragma unroll
            for (int j = 0; j < 8; j++) s += k5l[w * H_ + ty * 8 + j] * leakyf(acc[i][j], 0.02f);
            part[i][w] = s;
        }
    }
    __syncthreads();
    float* red = bl;  // 16*512 = 8192 floats
#pragma unroll
    for (int i = 0; i < 4; i++)
#pragma unroll
        for (int w = 0; w < 8; w++) red[ty * 512 + (tx * 4 + i) * 8 + w] = part[i][w];
    __syncthreads();
    for (int o = t; o < 512; o += 256) {
        float s = 0.f;
#pragma unroll
        for (int q = 0; q < 16; q++) s += red[q * 512 + o];
        int ee = o >> 3, w = o & 7;
        kern[((size_t)(b * P_ + p) * e_ + e0 + ee) * W_ + w] = fmaxf(s + k5b[p * W_ + w], 0.f);
    }
}

// ---------------- K4: y[b,p,n,w,f] = sum_e linc[p,n,e]*kern[b,p,e,w]*rx[b,p,e,f] ----------------
__global__ __launch_bounds__(256) void k_y(const float* __restrict__ linc,
                                           const float* __restrict__ kern,
                                           const float* __restrict__ rx,
                                           float* __restrict__ y) {
    const int w = blockIdx.x;
    const int p = blockIdx.y;
    const int b = blockIdx.z;
    const int t = threadIdx.x;
    const int fg = t & 15;  // f_sub = fg*4
    const int ng = t >> 4;  // n_sub = ng*8
    __shared__ float al[128 * 64];  // [nn][ee] swizzled
    __shared__ float rxl[64 * 64];  // [ee][f]  K-major
    __shared__ float kl[64];

    float acc[8][4];
#pragma unroll
    for (int i = 0; i < 8; i++)
#pragma unroll
        for (int j = 0; j < 4; j++) acc[i][j] = 0.f;

    for (int c = 0; c < 16; c++) {
        const int e0 = c * 64;
        __syncthreads();
        for (int idx = t; idx < 8192; idx += 256) {
            int nn = idx >> 6, ee = idx & 63;
            al[swz64(nn, ee)] = linc[(size_t)(p * n_ + nn) * e_ + e0 + ee];
        }
        for (int idx = t; idx < 4096; idx += 256) {
            int ee = idx >> 6, f = idx & 63;
            rxl[ee * 64 + f] = rx[((size_t)(b * P_ + p) * e_ + e0 + ee) * F_ + f];
        }
        if (t < 64) kl[t] = kern[((size_t)(b * P_ + p) * e_ + e0 + t) * W_ + w];
        __syncthreads();
#pragma unroll 2
        for (int k4 = 0; k4 < 16; k4++) {
            float4 lv[8];
#pragma unroll
            for (int i = 0; i < 8; i++) lv[i] = ld64(al, ng * 8 + i, k4);
            float4 kv = *reinterpret_cast<const float4*>(kl + k4 * 4);
            const float* kvp = reinterpret_cast<const float*>(&kv);
#pragma unroll
            for (int q = 0; q < 4; q++) {
                float4 xv = *reinterpret_cast<const float4*>(rxl + (k4 * 4 + q) * 64 + fg * 4);
#pragma unroll
                for (int i = 0; i < 8; i++) {
                    float a = reinterpret_cast<const float*>(&lv[i])[q] * kvp[q];
                    acc[i][0] += a * xv.x;
                    acc[i][1] += a * xv.y;
                    acc[i][2] += a * xv.z;
                    acc[i][3] += a * xv.w;
                }
            }
        }
    }
#pragma unroll
    for (int i = 0; i < 8; i++) {
        size_t off = ((((size_t)(b * P_ + p) * n_ + ng * 8 + i) * W_ + w) * F_) + fg * 4;
        *reinterpret_cast<float4*>(y + off) = make_float4(acc[i][0], acc[i][1], acc[i][2], acc[i][3]);
    }
}

// ---------------- K5: y2[b,p,n,g] = relu(gc_w[p,g,:]·y[b,p,n,:] + gc_b[p,g]) ----------------
__global__ __launch_bounds__(256) void k_gc(const float* __restrict__ gcw,
                                            const float* __restrict__ gcb,
                                            const float* __restrict__ y,
                                            float* __restrict__ y2) {
    const int p = blockIdx.x, b = blockIdx.y;
    const int t = threadIdx.x;
    const int tg = t & 15;  // g_sub = tg*8
    const int tn = t >> 4;  // n_sub = tn*8
    __shared__ float yl[128 * 64];  // [nn][kk] swizzled
    __shared__ float gl[128 * 64];  // [g][kk]  swizzled
    float acc[8][8];
#pragma unroll
    for (int i = 0; i < 8; i++)
#pragma unroll
        for (int j = 0; j < 8; j++) acc[i][j] = 0.f;

    for (int c = 0; c < 8; c++) {
        const int k0 = c * 64;
        __syncthreads();
        for (int idx = t; idx < 8192; idx += 256) {
            int r = idx >> 6, kk = idx & 63;
            yl[swz64(r, kk)] = y[((size_t)(b * P_ + p) * n_ + r) * 512 + k0 + kk];
            gl[swz64(r, kk)] = gcw[(size_t)(p * G_ + r) * 512 + k0 + kk];
        }
        __syncthreads();
#pragma unroll 2
        for (int k4 = 0; k4 < 16; k4++) {
            float4 yv[8];
#pragma unroll
            for (int i = 0; i < 8; i++) yv[i] = ld64(yl, tn * 8 + i, k4);
#pragma unroll
            for (int j = 0; j < 8; j++) {
                float4 gv = ld64(gl, tg * 8 + j, k4);
#pragma unroll
                for (int i = 0; i < 8; i++) {
                    acc[i][j] += yv[i].x * gv.x + yv[i].y * gv.y + yv[i].z * gv.z + yv[i].w * gv.w;
                }
            }
        }
    }
#pragma unroll
    for (int i = 0; i < 8; i++) {
        int nn = tn * 8 + i;
        size_t base = ((size_t)(b * P_ + p) * n_ + nn) * G_ + tg * 8;
        float4 v0 = make_float4(fmaxf(acc[i][0] + gcb[p * G_ + tg * 8 + 0], 0.f),
                                fmaxf(acc[i][1] + gcb[p * G_ + tg * 8 + 1], 0.f),
                                fmaxf(acc[i][2] + gcb[p * G_ + tg * 8 + 2], 0.f),
                                fmaxf(acc[i][3] + gcb[p * G_ + tg * 8 + 3], 0.f));
        float4 v1 = make_float4(fmaxf(acc[i][4] + gcb[p * G_ + tg * 8 + 4], 0.f),
                                fmaxf(acc[i][5] + gcb[p * G_ + tg * 8 + 5], 0.f),
                                fmaxf(acc[i][6] + gcb[p * G_ + tg * 8 + 6], 0.f),
                                fmaxf(acc[i][7] + gcb[p * G_ + tg * 8 + 7], 0.f));
        *reinterpret_cast<float4*>(y2 + base) = v0;
        *reinterpret_cast<float4*>(y2 + base + 4) = v1;
    }
}

// ---------------- K6: hpart[ks,p,r,b] = sum_{k in slice} r0_w[p,r,k]*y2flat[b,p,k] ----------------
__global__ __launch_bounds__(256) void k_h1(const float* __restrict__ r0w,
                                            const float* __restrict__ y2,
                                            float* __restrict__ hpart) {
    const int ks = blockIdx.x;  // 0..63, 256 k each
    const int p = blockIdx.y;
    const int t = threadIdx.x;
    const int bg = t & 7;   // b = bg*4 + j
    const int rg = t >> 3;  // r = rg*8 + i
    __shared__ float yl[32 * 256];  // [b][k] swizzled by (b>>2)&7
    const int kc = ks * 256;
    for (int idx = t; idx < 8192; idx += 256) {
        int bb = idx >> 8, kk = idx & 255;
        yl[bb * 256 + ((((kk >> 2) ^ ((bb >> 2) & 7)) << 2) | (kk & 3))] =
            y2[(size_t)(bb * P_ + p) * (n_ * G_) + kc + kk];
    }
    __syncthreads();
    float acc[8][4];
#pragma unroll
    for (int i = 0; i < 8; i++)
#pragma unroll
        for (int j = 0; j < 4; j++) acc[i][j] = 0.f;

    for (int run = 0; run < 16; run++) {
        float4 y2v[4][4];
#pragma unroll
        for (int j = 0; j < 4; j++) {
            int bb = bg * 4 + j;
            int sw = (bb >> 2) & 7;
#pragma unroll
            for (int q = 0; q < 4; q++) {
                int c4 = (run * 4 + q) ^ sw;
                y2v[j][q] = *reinterpret_cast<const float4*>(yl + bb * 256 + (c4 << 2));
            }
        }
#pragma unroll
        for (int i = 0; i < 8; i++) {
            int r = rg * 8 + i;
            const float4* r0p =
                reinterpret_cast<const float4*>(r0w + (size_t)(p * R_ + r) * 16384 + kc + run * 16);
            float4 r0v[4];
#pragma unroll
            for (int q = 0; q < 4; q++) r0v[q] = r0p[q];
#pragma unroll
            for (int j = 0; j < 4; j++) {
#pragma unroll
                for (int q = 0; q < 4; q++) {
                    acc[i][j] += r0v[q].x * y2v[j][q].x + r0v[q].y * y2v[j][q].y +
                                 r0v[q].z * y2v[j][q].z + r0v[q].w * y2v[j][q].w;
                }
            }
        }
    }
#pragma unroll
    for (int i = 0; i < 8; i++) {
        size_t off = ((size_t)(ks * P_ + p) * R_ + rg * 8 + i) * 32 + bg * 4;
        *reinterpret_cast<float4*>(hpart + off) = make_float4(acc[i][0], acc[i][1], acc[i][2], acc[i][3]);
    }
}

// ---------------- K7: h -> leaky -> w -> res ----------------
__global__ __launch_bounds__(128) void k_wres(const float* __restrict__ hpart,
                                              const float* __restrict__ r1w,
                                              const float* __restrict__ r1b,
                                              const float* __restrict__ r2w,
                                              const float* __restrict__ cap,
                                              const float* __restrict__ tin,
                                              const float* __restrict__ r3w,
                                              const float* __restrict__ r3b,
                                              const float* __restrict__ y2,
                                              float* __restrict__ res) {
    const int p = blockIdx.x, b = blockIdx.y;
    const int t = threadIdx.x;
    __shared__ float lh[256];
    __shared__ float wl[128];
    for (int rr = t; rr < 256; rr += 128) {
        float s = 0.f;
        for (int ks = 0; ks < 64; ks++) s += hpart[((size_t)(ks * P_ + p) * R_ + rr) * 32 + b];
        for (int tt = 0; tt < T_; tt++) s += r1w[(size_t)(p * R_ + rr) * T_ + tt] * tin[b * T_ + tt];
        s += r1b[p * R_ + rr];
        for (int nn = 0; nn < n_; nn++) s += r2w[(size_t)(p * R_ + rr) * n_ + nn] * cap[p * n_ + nn];
        lh[rr] = leakyf(s, 0.01f);
    }
    __syncthreads();
    {
        const int nn = t;
        float accw = r3b[p * n_ + nn];
        const float* r3p = r3w + (size_t)(p * n_ + nn) * R_;
        for (int r = 0; r < 256; r += 4) {
            float4 rv = *reinterpret_cast<const float4*>(r3p + r);
            accw += rv.x * lh[r] + rv.y * lh[r + 1] + rv.z * lh[r + 2] + rv.w * lh[r + 3];
        }
        wl[nn] = fmaxf(accw, 0.f);
    }
    __syncthreads();
    {
        const int g = t;
        float a = 0.f;
        for (int nn = 0; nn < n_; nn++) a += wl[nn] * y2[((size_t)(b * P_ + p) * n_ + nn) * G_ + g];
        res[(b * P_ + p) * G_ + g] = a;
    }
}

// ---------------- K8: out[b,l] = leaky(sum_{g,p} conv_w[l,g,p]*res[b,p,g] + conv_b[l]) ----------------
__global__ __launch_bounds__(128) void k_out(const float* __restrict__ convw,
                                             const float* __restrict__ convb,
                                             const float* __restrict__ res,
                                             float* __restrict__ out) {
    const int b = blockIdx.x;
    const int t = threadIdx.x;  // l
    __shared__ float rl[1024];  // [p][g]
    for (int idx = t; idx < 1024; idx += 128) rl[idx] = res[b * 1024 + idx];
    __syncthreads();
    float a = convb[t];
    const float* cw = convw + (size_t)t * 1024;  // row l: [g][p]
    for (int gp = 0; gp < 1024; gp += 4) {
        float4 v = *reinterpret_cast<const float4*>(cw + gp);
        a += v.x * rl[((gp + 0) & 7) * 128 + ((gp + 0) >> 3)];
        a += v.y * rl[((gp + 1) & 7) * 128 + ((gp + 1) >> 3)];
        a += v.z * rl[((gp + 2) & 7) * 128 + ((gp + 2) >> 3)];
        a += v.w * rl[((gp + 3) & 7) * 128 + ((gp + 3) >> 3)];
    }
    out[b * L2_ + t] = leakyf(a, 0.02f);
}

extern "C" void kernel_launch(void* const* d_in, const int* in_sizes, int n_in,
                              void* d_out, int out_size, void* d_ws, size_t ws_size,
                              hipStream_t stream) {
    const float* x    = (const float*)d_in[0];
    const float* tin  = (const float*)d_in[1];
    const float* ef   = (const float*)d_in[2];
    const float* linc = (const float*)d_in[3];
    const float* rinc = (const float*)d_in[4];
    const float* cap  = (const float*)d_in[5];
    const float* k1w  = (const float*)d_in[6];
    const float* k1b  = (const float*)d_in[7];
    const float* k2w  = (const float*)d_in[8];
    const float* k3w  = (const float*)d_in[9];
    const float* k4w  = (const float*)d_in[10];
    const float* k5w  = (const float*)d_in[11];
    const float* k5b  = (const float*)d_in[12];
    const float* gcw  = (const float*)d_in[13];
    const float* gcb  = (const float*)d_in[14];
    const float* r0w  = (const float*)d_in[15];
    const float* r1w  = (const float*)d_in[16];
    const float* r1b  = (const float*)d_in[17];
    const float* r2w  = (const float*)d_in[18];
    const float* r3w  = (const float*)d_in[19];
    const float* r3b  = (const float*)d_in[20];
    const float* convw = (const float*)d_in[21];
    const float* convb = (const float*)d_in[22];
    const int* nodes  = (const int*)d_in[23];
    const int* nbr    = (const int*)d_in[24];
    float* out = (float*)d_out;

    float* ws = (float*)d_ws;
    // layout (floats): rx[16M] | y[16M] (u aliases head) | kern[2M] | y2[4M]
    float* rxb   = ws;                 // 16777216 floats, dead after k_y
    float* yb    = ws + 16777216;      // 16777216 floats
    float* ub    = yb;                 // 4194304 floats, dead before k_y writes yb
    float* kernb = ws + 33554432;      // 2097152 floats
    float* y2b   = ws + 35651584;      // 4194304 floats
    float* hpart = rxb;                // 4194304 floats (aliases rx, dead by then)
    float* resb  = rxb + 4194304;      // 32768 floats

    k_rx  <<<dim3(16, P_, B_), 256, 0, stream>>>(x, rinc, nbr, rxb);
    k_u   <<<dim3(P_, B_),     256, 0, stream>>>(x, k3w, nodes, ub);
    k_kern<<<dim3(16, P_, B_), 256, 0, stream>>>(linc, ub, rxb, k4w, ef, k1w, k1b, tin, k2w, k5w, k5b, kernb);
    k_y   <<<dim3(W_, P_, B_), 256, 0, stream>>>(linc, kernb, rxb, yb);
    k_gc  <<<dim3(P_, B_),     256, 0, stream>>>(gcw, gcb, yb, y2b);
    k_h1  <<<dim3(64, P_),     256, 0, stream>>>(r0w, y2b, hpart);
    k_wres<<<dim3(P_, B_),     128, 0, stream>>>(hpart, r1w, r1b, r2w, cap, tin, r3w, r3b, y2b, resb);
    k_out <<<B_, 128, 0, stream>>>(convw, convb, resb, out);
}

// Round 2
// 711.883 us; speedup vs baseline: 2.0425x; 2.0425x over previous
//
#include <hip/hip_runtime.h>
#include <math.h>

#define B_ 32
#define N_ 1024
#define F_ 64
#define P_ 8
#define n_ 128
#define m_ 256
#define e_ 1024
#define EF_ 8
#define T_ 16
#define H_ 128
#define W_ 8
#define G_ 128
#define R_ 256
#define L2_ 128

typedef unsigned short u16;
typedef unsigned int u32;
typedef __attribute__((ext_vector_type(8))) short bf16x8;
typedef __attribute__((ext_vector_type(4))) float f32x4;

__device__ __forceinline__ float leakyf(float z, float s) { return z >= 0.f ? z : s * z; }

__device__ __forceinline__ u16 f2bf(float f) {
    u32 u = __float_as_uint(f);
    u += 0x7FFFu + ((u >> 16) & 1u);
    return (u16)(u >> 16);
}
__device__ __forceinline__ float bf2f(u16 h) { return __uint_as_float(((u32)h) << 16); }

// ---- f32 LDS helpers (for remaining f32 kernels) ----
__device__ __forceinline__ int swz64(int r, int c) {
    return r * 64 + ((((c >> 2) ^ ((r >> 3) & 15)) << 2) | (c & 3));
}
__device__ __forceinline__ float4 ld64(const float* lds, int r, int c4) {
    return *reinterpret_cast<const float4*>(lds + r * 64 + ((c4 ^ ((r >> 3) & 15)) << 2));
}

// ---- bf16 LDS tile: [rows][64] u16, 8 chunks of 8 bf16 per row, chunk ^= row&7 ----
__device__ __forceinline__ int swzi(int row, int col) {  // u16 index, scalar access
    return row * 64 + ((((col >> 3) ^ (row & 7)) << 3) | (col & 7));
}
__device__ __forceinline__ bf16x8 ldfrag(const u16* lds, int row, int kb) {  // kb multiple of 8
    return *reinterpret_cast<const bf16x8*>(lds + row * 64 + ((((kb >> 3) ^ (row & 7)) << 3)));
}

// ---------------- prep: f32 -> bf16 copies of linc, rinc, gcw ----------------
__global__ __launch_bounds__(256) void k_prep(const float* __restrict__ linc,
                                              const float* __restrict__ rinc,
                                              const float* __restrict__ gcw,
                                              u16* __restrict__ lincbf,
                                              u16* __restrict__ rincbf,
                                              u16* __restrict__ gcwbf) {
    int i = blockIdx.x * 256 + threadIdx.x;  // one float4 each
    const float* src;
    u16* dst;
    int base;
    if (i < 262144) { src = linc; dst = lincbf; base = 0; }
    else if (i < 786432) { src = rinc; dst = rincbf; base = 262144; }
    else { src = gcw; dst = gcwbf; base = 786432; }
    int j = i - base;
    float4 v = reinterpret_cast<const float4*>(src)[j];
    ushort4 o = make_ushort4(f2bf(v.x), f2bf(v.y), f2bf(v.z), f2bf(v.w));
    reinterpret_cast<ushort4*>(dst)[j] = o;
}

// ---------------- K1 (MFMA): rx[b,p,e,f] = sum_m rinc[p,e,m] * x[b,nbr[p,m],f] ----------------
__global__ __launch_bounds__(256) void k_rx(const float* __restrict__ x,
                                            const u16* __restrict__ rincbf,
                                            const int* __restrict__ nbr,
                                            u16* __restrict__ rxbf) {
    const int et = blockIdx.x, p = blockIdx.y, b = blockIdx.z;
    const int t = threadIdx.x, lane = t & 63, wid = t >> 6;
    __shared__ __align__(16) u16 A_lds[128 * 64];   // [e-local][m-chunk]
    __shared__ __align__(16) u16 BT_lds[64 * 64];   // [f][m-chunk]
    f32x4 acc[2][4];
#pragma unroll
    for (int i = 0; i < 2; i++)
#pragma unroll
        for (int j = 0; j < 4; j++) acc[i][j] = 0.f;

    const int e0 = et * 128;
    for (int c = 0; c < 4; c++) {
        const int m0 = c * 64;
        __syncthreads();
        {   // A: copy rincbf rows (already bf16)
            int ee = t >> 1, seg = t & 1;
            const uint4* src = reinterpret_cast<const uint4*>(
                rincbf + ((size_t)(p * e_ + e0 + ee) * m_ + m0 + seg * 32));
#pragma unroll
            for (int q = 0; q < 4; q++) {
                uint4 v = src[q];
                int ch = (seg * 4 + q) ^ (ee & 7);
                *reinterpret_cast<uint4*>(A_lds + ee * 64 + ch * 8) = v;
            }
        }
        {   // B: gather x rows, cvt, transpose into BT[f][m]
            int mm = t >> 2, fq = (t & 3) * 16;
            int row = nbr[p * m_ + m0 + mm];
            const float4* sx = reinterpret_cast<const float4*>(
                x + (size_t)(b * N_ + row) * F_ + fq);
#pragma unroll
            for (int q = 0; q < 4; q++) {
                float4 v = sx[q];
                int f0 = fq + q * 4;
                BT_lds[swzi(f0 + 0, mm)] = f2bf(v.x);
                BT_lds[swzi(f0 + 1, mm)] = f2bf(v.y);
                BT_lds[swzi(f0 + 2, mm)] = f2bf(v.z);
                BT_lds[swzi(f0 + 3, mm)] = f2bf(v.w);
            }
        }
        __syncthreads();
        const int wm0 = wid * 32, r15 = lane & 15, g4 = lane >> 4;
#pragma unroll
        for (int ks = 0; ks < 2; ks++) {
            int kb = ks * 32 + g4 * 8;
            bf16x8 af[2], bfr[4];
#pragma unroll
            for (int mf = 0; mf < 2; mf++) af[mf] = ldfrag(A_lds, wm0 + mf * 16 + r15, kb);
#pragma unroll
            for (int nf = 0; nf < 4; nf++) bfr[nf] = ldfrag(BT_lds, nf * 16 + r15, kb);
#pragma unroll
            for (int mf = 0; mf < 2; mf++)
#pragma unroll
                for (int nf = 0; nf < 4; nf++)
                    acc[mf][nf] = __builtin_amdgcn_mfma_f32_16x16x32_bf16(af[mf], bfr[nf], acc[mf][nf], 0, 0, 0);
        }
    }
    const int r15 = lane & 15, g4 = lane >> 4;
#pragma unroll
    for (int mf = 0; mf < 2; mf++)
#pragma unroll
        for (int nf = 0; nf < 4; nf++)
#pragma unroll
            for (int r = 0; r < 4; r++) {
                int erow = e0 + wid * 32 + mf * 16 + g4 * 4 + r;
                int f = nf * 16 + r15;
                rxbf[((size_t)(b * P_ + p) * e_ + erow) * F_ + f] = f2bf(acc[mf][nf][r]);
            }
}

// ---------------- K2: u[b,p,n,h] = sum_f k3_w[p,h,f] * x[b,nodes[p,n],f]  (f32) ----------------
__global__ __launch_bounds__(256) void k_u(const float* __restrict__ x,
                                           const float* __restrict__ k3w,
                                           const int* __restrict__ nodes,
                                           float* __restrict__ u) {
    const int p = blockIdx.x, b = blockIdx.y;
    const int t = threadIdx.x;
    const int th = t & 15;
    const int tn = t >> 4;
    __shared__ float xg[128 * 64];
    __shared__ float kw[128 * 64];
    for (int idx = t; idx < 8192; idx += 256) {
        int r = idx >> 6, f = idx & 63;
        int row = nodes[p * n_ + r];
        xg[swz64(r, f)] = x[(size_t)(b * N_ + row) * F_ + f];
        kw[swz64(r, f)] = k3w[(size_t)(p * H_ + r) * F_ + f];
    }
    __syncthreads();
    float acc[8][8];
#pragma unroll
    for (int i = 0; i < 8; i++)
#pragma unroll
        for (int j = 0; j < 8; j++) acc[i][j] = 0.f;
#pragma unroll 2
    for (int k4 = 0; k4 < 16; k4++) {
        float4 xv[8];
#pragma unroll
        for (int i = 0; i < 8; i++) xv[i] = ld64(xg, tn * 8 + i, k4);
#pragma unroll
        for (int j = 0; j < 8; j++) {
            float4 kv = ld64(kw, th * 8 + j, k4);
#pragma unroll
            for (int i = 0; i < 8; i++) {
                acc[i][j] += xv[i].x * kv.x + xv[i].y * kv.y + xv[i].z * kv.z + xv[i].w * kv.w;
            }
        }
    }
#pragma unroll
    for (int i = 0; i < 8; i++) {
        size_t base = ((size_t)(b * P_ + p) * n_ + tn * 8 + i) * H_ + th * 8;
        *reinterpret_cast<float4*>(u + base) = make_float4(acc[i][0], acc[i][1], acc[i][2], acc[i][3]);
        *reinterpret_cast<float4*>(u + base + 4) = make_float4(acc[i][4], acc[i][5], acc[i][6], acc[i][7]);
    }
}

// ---------------- K3: kernel[b,p,e,w]  (f32, fused K=217 GEMM + leaky + k5) ----------------
__global__ __launch_bounds__(256) void k_kern(const float* __restrict__ linc,
                                              const float* __restrict__ u,
                                              const u16* __restrict__ rxbf,
                                              const float* __restrict__ k4w,
                                              const float* __restrict__ ef,
                                              const float* __restrict__ k1w,
                                              const float* __restrict__ k1b,
                                              const float* __restrict__ tin,
                                              const float* __restrict__ k2w,
                                              const float* __restrict__ k5w,
                                              const float* __restrict__ k5b,
                                              float* __restrict__ kern) {
    const int et = blockIdx.x;  // e-tile (64)
    const int p = blockIdx.y;
    const int b = blockIdx.z;
    const int t = threadIdx.x;
    const int tx = t & 15;
    const int ty = t >> 4;
    __shared__ float al[64 * 64];
    __shared__ float bl[64 * 128];
    __shared__ float k5l[8 * 128];

    for (int idx = t; idx < 1024; idx += 256) k5l[idx] = k5w[p * W_ * H_ + idx];

    float acc[4][8];
#pragma unroll
    for (int i = 0; i < 4; i++)
#pragma unroll
        for (int j = 0; j < 8; j++) acc[i][j] = 0.f;

    const int e0 = et * 64;
    const size_t pb_e = (size_t)(b * P_ + p) * e_;
    for (int c = 0; c < 4; c++) {
        const int k0 = c * 64;
        __syncthreads();
        for (int idx = t; idx < 4096; idx += 256) {
            int kl = idx >> 6, ee = idx & 63;
            int kg = k0 + kl;
            float v;
            if (kg < 128)      v = linc[(size_t)(p * n_ + kg) * e_ + e0 + ee];
            else if (kg < 192) v = bf2f(rxbf[(pb_e + e0 + ee) * F_ + (kg - 128)]);
            else if (kg < 200) v = ef[(size_t)(p * e_ + e0 + ee) * (EF_ + 1) + (kg - 192)];
            else if (kg < 216) v = tin[b * T_ + (kg - 200)];
            else if (kg == 216) v = 1.0f;
            else               v = 0.f;
            al[kl * 64 + ee] = v;
        }
        for (int idx = t; idx < 8192; idx += 256) {
            int kl = idx >> 7, h = idx & 127;
            int kg = k0 + kl;
            float v;
            if (kg < 128)      v = u[((size_t)(b * P_ + p) * n_ + kg) * H_ + h];
            else if (kg < 192) v = k4w[(size_t)(p * H_ + h) * F_ + (kg - 128)];
            else if (kg < 200) v = k1w[(size_t)(p * H_ + h) * EF_ + (kg - 192)];
            else if (kg < 216) v = k2w[(size_t)(p * H_ + h) * T_ + (kg - 200)];
            else if (kg == 216) v = k1b[p * H_ + h];
            else               v = 0.f;
            bl[kl * 128 + h] = v;
        }
        __syncthreads();
#pragma unroll 4
        for (int kk = 0; kk < 64; kk++) {
            float4 a4 = *reinterpret_cast<const float4*>(al + kk * 64 + tx * 4);
            float4 b4a = *reinterpret_cast<const float4*>(bl + kk * 128 + ty * 8);
            float4 b4b = *reinterpret_cast<const float4*>(bl + kk * 128 + ty * 8 + 4);
            const float* ap = reinterpret_cast<const float*>(&a4);
            const float* bpa = reinterpret_cast<const float*>(&b4a);
            const float* bpb = reinterpret_cast<const float*>(&b4b);
#pragma unroll
            for (int i = 0; i < 4; i++) {
#pragma unroll
                for (int j = 0; j < 4; j++) {
                    acc[i][j] += ap[i] * bpa[j];
                    acc[i][j + 4] += ap[i] * bpb[j];
                }
            }
        }
    }
    float part[4][8];
#pragma unroll
    for (int i = 0; i < 4; i++) {
#pragma unroll
        for (int w = 0; w < 8; w++) {
            float s = 0.f;
#pragma unroll
            for (int j = 0; j < 8; j++) s += k5l[w * H_ + ty * 8 + j] * leakyf(acc[i][j], 0.02f);
            part[i][w] = s;
        }
    }
    __syncthreads();
    float* red = bl;
#pragma unroll
    for (int i = 0; i < 4; i++)
#pragma unroll
        for (int w = 0; w < 8; w++) red[ty * 512 + (tx * 4 + i) * 8 + w] = part[i][w];
    __syncthreads();
    for (int o = t; o < 512; o += 256) {
        float s = 0.f;
#pragma unroll
        for (int q = 0; q < 16; q++) s += red[q * 512 + o];
        int ee = o >> 3, w = o & 7;
        kern[(pb_e + e0 + ee) * W_ + w] = fmaxf(s + k5b[p * W_ + w], 0.f);
    }
}

// ---------------- K4 (MFMA): Q[b,p,e,g] = sum_{w,f} (kern[e,w]*rx[e,f]) * gcw[g,w*F+f] ----------------
__global__ __launch_bounds__(256) void k_q(const u16* __restrict__ rxbf,
                                           const float* __restrict__ kernb,
                                           const u16* __restrict__ gcwbf,
                                           u16* __restrict__ Qbf) {
    const int et = blockIdx.x, p = blockIdx.y, b = blockIdx.z;
    const int t = threadIdx.x, lane = t & 63, wid = t >> 6;
    __shared__ __align__(16) u16 A_lds[128 * 64];   // [e-local][k-chunk] = kern*rx
    __shared__ __align__(16) u16 BT_lds[128 * 64];  // [g][k-chunk] = gcw rows
    f32x4 acc[4][4];
#pragma unroll
    for (int i = 0; i < 4; i++)
#pragma unroll
        for (int j = 0; j < 4; j++) acc[i][j] = 0.f;

    const int e0 = et * 128;
    const size_t pb_e = (size_t)(b * P_ + p) * e_;
    const int wm = (wid >> 1) * 64, wn = (wid & 1) * 64;
    const int r15 = lane & 15, g4 = lane >> 4;

    for (int w = 0; w < 8; w++) {
        __syncthreads();
        {   // A: bf16(kern[e,w] * rx[e,f])
            int ee = t >> 1, seg = t & 1;
            float ksc = kernb[(pb_e + e0 + ee) * W_ + w];
            const uint4* src = reinterpret_cast<const uint4*>(rxbf + (pb_e + e0 + ee) * F_ + seg * 32);
#pragma unroll
            for (int q = 0; q < 4; q++) {
                uint4 v = src[q];
                u32 vv[4] = {v.x, v.y, v.z, v.w};
                u32 ov[4];
#pragma unroll
                for (int q2 = 0; q2 < 4; q2++) {
                    float f0 = bf2f((u16)(vv[q2] & 0xFFFF)) * ksc;
                    float f1 = bf2f((u16)(vv[q2] >> 16)) * ksc;
                    ov[q2] = (u32)f2bf(f0) | ((u32)f2bf(f1) << 16);
                }
                int ch = (seg * 4 + q) ^ (ee & 7);
                *reinterpret_cast<uint4*>(A_lds + ee * 64 + ch * 8) =
                    make_uint4(ov[0], ov[1], ov[2], ov[3]);
            }
        }
        {   // B: copy gcwbf rows [g][w*64 .. +64]
            int gg = t >> 1, seg = t & 1;
            const uint4* src = reinterpret_cast<const uint4*>(
                gcwbf + (size_t)(p * G_ + gg) * 512 + w * 64 + seg * 32);
#pragma unroll
            for (int q = 0; q < 4; q++) {
                uint4 v = src[q];
                int ch = (seg * 4 + q) ^ (gg & 7);
                *reinterpret_cast<uint4*>(BT_lds + gg * 64 + ch * 8) = v;
            }
        }
        __syncthreads();
#pragma unroll
        for (int ks = 0; ks < 2; ks++) {
            int kb = ks * 32 + g4 * 8;
            bf16x8 af[4], bfr[4];
#pragma unroll
            for (int mf = 0; mf < 4; mf++) af[mf] = ldfrag(A_lds, wm + mf * 16 + r15, kb);
#pragma unroll
            for (int nf = 0; nf < 4; nf++) bfr[nf] = ldfrag(BT_lds, wn + nf * 16 + r15, kb);
#pragma unroll
            for (int mf = 0; mf < 4; mf++)
#pragma unroll
                for (int nf = 0; nf < 4; nf++)
                    acc[mf][nf] = __builtin_amdgcn_mfma_f32_16x16x32_bf16(af[mf], bfr[nf], acc[mf][nf], 0, 0, 0);
        }
    }
#pragma unroll
    for (int mf = 0; mf < 4; mf++)
#pragma unroll
        for (int nf = 0; nf < 4; nf++)
#pragma unroll
            for (int r = 0; r < 4; r++) {
                int erow = e0 + wm + mf * 16 + g4 * 4 + r;
                int g = wn + nf * 16 + r15;
                Qbf[(pb_e + erow) * G_ + g] = f2bf(acc[mf][nf][r]);
            }
}

// ---------------- K5 (MFMA): y2[b,p,n,g] = relu(sum_e linc[n,e]*Q[e,g] + gcb[g]) ----------------
__global__ __launch_bounds__(256) void k_y2(const u16* __restrict__ lincbf,
                                            const u16* __restrict__ Qbf,
                                            const float* __restrict__ gcb,
                                            float* __restrict__ y2) {
    const int p = blockIdx.x, b = blockIdx.y;
    const int t = threadIdx.x, lane = t & 63, wid = t >> 6;
    __shared__ __align__(16) u16 A_lds[128 * 64];   // [n][e-chunk]
    __shared__ __align__(16) u16 BT_lds[128 * 64];  // [g][e-chunk] (transposed Q)
    f32x4 acc[4][4];
#pragma unroll
    for (int i = 0; i < 4; i++)
#pragma unroll
        for (int j = 0; j < 4; j++) acc[i][j] = 0.f;

    const size_t pb_e = (size_t)(b * P_ + p) * e_;
    const int wm = (wid >> 1) * 64, wn = (wid & 1) * 64;
    const int r15 = lane & 15, g4 = lane >> 4;

    for (int c = 0; c < 16; c++) {
        const int e0 = c * 64;
        __syncthreads();
        {   // A: linc rows (bf16 copy)
            int nn = t >> 1, seg = t & 1;
            const uint4* src = reinterpret_cast<const uint4*>(
                lincbf + (size_t)(p * n_ + nn) * e_ + e0 + seg * 32);
#pragma unroll
            for (int q = 0; q < 4; q++) {
                uint4 v = src[q];
                int ch = (seg * 4 + q) ^ (nn & 7);
                *reinterpret_cast<uint4*>(A_lds + nn * 64 + ch * 8) = v;
            }
        }
        {   // B: transpose Q[e][g] -> BT[g][e-local]
            int ek = t >> 2, gq = (t & 3) * 32;
            const uint4* src = reinterpret_cast<const uint4*>(Qbf + (pb_e + e0 + ek) * G_ + gq);
#pragma unroll
            for (int q = 0; q < 4; q++) {
                uint4 v = src[q];
                u32 vv[4] = {v.x, v.y, v.z, v.w};
#pragma unroll
                for (int q2 = 0; q2 < 4; q2++) {
                    int g0 = gq + q * 8 + q2 * 2;
                    BT_lds[swzi(g0, ek)] = (u16)(vv[q2] & 0xFFFF);
                    BT_lds[swzi(g0 + 1, ek)] = (u16)(vv[q2] >> 16);
                }
            }
        }
        __syncthreads();
#pragma unroll
        for (int ks = 0; ks < 2; ks++) {
            int kb = ks * 32 + g4 * 8;
            bf16x8 af[4], bfr[4];
#pragma unroll
            for (int mf = 0; mf < 4; mf++) af[mf] = ldfrag(A_lds, wm + mf * 16 + r15, kb);
#pragma unroll
            for (int nf = 0; nf < 4; nf++) bfr[nf] = ldfrag(BT_lds, wn + nf * 16 + r15, kb);
#pragma unroll
            for (int mf = 0; mf < 4; mf++)
#pragma unroll
                for (int nf = 0; nf < 4; nf++)
                    acc[mf][nf] = __builtin_amdgcn_mfma_f32_16x16x32_bf16(af[mf], bfr[nf], acc[mf][nf], 0, 0, 0);
        }
    }
#pragma unroll
    for (int mf = 0; mf < 4; mf++)
#pragma unroll
        for (int nf = 0; nf < 4; nf++) {
            int g = wn + nf * 16 + r15;
            float gb = gcb[p * G_ + g];
#pragma unroll
            for (int r = 0; r < 4; r++) {
                int nrow = wm + mf * 16 + g4 * 4 + r;
                y2[((size_t)(b * P_ + p) * n_ + nrow) * G_ + g] = fmaxf(acc[mf][nf][r] + gb, 0.f);
            }
        }
}

// ---------------- K6: hpart[ks,p,r,b] = sum_{k in slice} r0_w[p,r,k]*y2flat[b,p,k] ----------------
__global__ __launch_bounds__(256) void k_h1(const float* __restrict__ r0w,
                                            const float* __restrict__ y2,
                                            float* __restrict__ hpart) {
    const int ks = blockIdx.x;
    const int p = blockIdx.y;
    const int t = threadIdx.x;
    const int bg = t & 7;
    const int rg = t >> 3;
    __shared__ float yl[32 * 256];
    const int kc = ks * 256;
    for (int idx = t; idx < 8192; idx += 256) {
        int bb = idx >> 8, kk = idx & 255;
        yl[bb * 256 + ((((kk >> 2) ^ ((bb >> 2) & 7)) << 2) | (kk & 3))] =
            y2[(size_t)(bb * P_ + p) * (n_ * G_) + kc + kk];
    }
    __syncthreads();
    float acc[8][4];
#pragma unroll
    for (int i = 0; i < 8; i++)
#pragma unroll
        for (int j = 0; j < 4; j++) acc[i][j] = 0.f;

    for (int run = 0; run < 16; run++) {
        float4 y2v[4][4];
#pragma unroll
        for (int j = 0; j < 4; j++) {
            int bb = bg * 4 + j;
            int sw = (bb >> 2) & 7;
#pragma unroll
            for (int q = 0; q < 4; q++) {
                int c4 = (run * 4 + q) ^ sw;
                y2v[j][q] = *reinterpret_cast<const float4*>(yl + bb * 256 + (c4 << 2));
            }
        }
#pragma unroll
        for (int i = 0; i < 8; i++) {
            int r = rg * 8 + i;
            const float4* r0p =
                reinterpret_cast<const float4*>(r0w + (size_t)(p * R_ + r) * 16384 + kc + run * 16);
            float4 r0v[4];
#pragma unroll
            for (int q = 0; q < 4; q++) r0v[q] = r0p[q];
#pragma unroll
            for (int j = 0; j < 4; j++) {
#pragma unroll
                for (int q = 0; q < 4; q++) {
                    acc[i][j] += r0v[q].x * y2v[j][q].x + r0v[q].y * y2v[j][q].y +
                                 r0v[q].z * y2v[j][q].z + r0v[q].w * y2v[j][q].w;
                }
            }
        }
    }
#pragma unroll
    for (int i = 0; i < 8; i++) {
        size_t off = ((size_t)(ks * P_ + p) * R_ + rg * 8 + i) * 32 + bg * 4;
        *reinterpret_cast<float4*>(hpart + off) = make_float4(acc[i][0], acc[i][1], acc[i][2], acc[i][3]);
    }
}

// ---------------- K7: h -> leaky -> w -> res ----------------
__global__ __launch_bounds__(128) void k_wres(const float* __restrict__ hpart,
                                              const float* __restrict__ r1w,
                                              const float* __restrict__ r1b,
                                              const float* __restrict__ r2w,
                                              const float* __restrict__ cap,
                                              const float* __restrict__ tin,
                                              const float* __restrict__ r3w,
                                              const float* __restrict__ r3b,
                                              const float* __restrict__ y2,
                                              float* __restrict__ res) {
    const int p = blockIdx.x, b = blockIdx.y;
    const int t = threadIdx.x;
    __shared__ float lh[256];
    __shared__ float wl[128];
    for (int rr = t; rr < 256; rr += 128) {
        float s = 0.f;
        for (int ks = 0; ks < 64; ks++) s += hpart[((size_t)(ks * P_ + p) * R_ + rr) * 32 + b];
        for (int tt = 0; tt < T_; tt++) s += r1w[(size_t)(p * R_ + rr) * T_ + tt] * tin[b * T_ + tt];
        s += r1b[p * R_ + rr];
        for (int nn = 0; nn < n_; nn++) s += r2w[(size_t)(p * R_ + rr) * n_ + nn] * cap[p * n_ + nn];
        lh[rr] = leakyf(s, 0.01f);
    }
    __syncthreads();
    {
        const int nn = t;
        float accw = r3b[p * n_ + nn];
        const float* r3p = r3w + (size_t)(p * n_ + nn) * R_;
        for (int r = 0; r < 256; r += 4) {
            float4 rv = *reinterpret_cast<const float4*>(r3p + r);
            accw += rv.x * lh[r] + rv.y * lh[r + 1] + rv.z * lh[r + 2] + rv.w * lh[r + 3];
        }
        wl[nn] = fmaxf(accw, 0.f);
    }
    __syncthreads();
    {
        const int g = t;
        float a = 0.f;
        for (int nn = 0; nn < n_; nn++) a += wl[nn] * y2[((size_t)(b * P_ + p) * n_ + nn) * G_ + g];
        res[(b * P_ + p) * G_ + g] = a;
    }
}

// ---------------- K8: out[b,l] ----------------
__global__ __launch_bounds__(128) void k_out(const float* __restrict__ convw,
                                             const float* __restrict__ convb,
                                             const float* __restrict__ res,
                                             float* __restrict__ out) {
    const int b = blockIdx.x;
    const int t = threadIdx.x;
    __shared__ float rl[1024];
    for (int idx = t; idx < 1024; idx += 128) rl[idx] = res[b * 1024 + idx];
    __syncthreads();
    float a = convb[t];
    const float* cw = convw + (size_t)t * 1024;
    for (int gp = 0; gp < 1024; gp += 4) {
        float4 v = *reinterpret_cast<const float4*>(cw + gp);
        a += v.x * rl[((gp + 0) & 7) * 128 + ((gp + 0) >> 3)];
        a += v.y * rl[((gp + 1) & 7) * 128 + ((gp + 1) >> 3)];
        a += v.z * rl[((gp + 2) & 7) * 128 + ((gp + 2) >> 3)];
        a += v.w * rl[((gp + 3) & 7) * 128 + ((gp + 3) >> 3)];
    }
    out[b * L2_ + t] = leakyf(a, 0.02f);
}

extern "C" void kernel_launch(void* const* d_in, const int* in_sizes, int n_in,
                              void* d_out, int out_size, void* d_ws, size_t ws_size,
                              hipStream_t stream) {
    const float* x    = (const float*)d_in[0];
    const float* tin  = (const float*)d_in[1];
    const float* ef   = (const float*)d_in[2];
    const float* linc = (const float*)d_in[3];
    const float* rinc = (const float*)d_in[4];
    const float* cap  = (const float*)d_in[5];
    const float* k1w  = (const float*)d_in[6];
    const float* k1b  = (const float*)d_in[7];
    const float* k2w  = (const float*)d_in[8];
    const float* k3w  = (const float*)d_in[9];
    const float* k4w  = (const float*)d_in[10];
    const float* k5w  = (const float*)d_in[11];
    const float* k5b  = (const float*)d_in[12];
    const float* gcw  = (const float*)d_in[13];
    const float* gcb  = (const float*)d_in[14];
    const float* r0w  = (const float*)d_in[15];
    const float* r1w  = (const float*)d_in[16];
    const float* r1b  = (const float*)d_in[17];
    const float* r2w  = (const float*)d_in[18];
    const float* r3w  = (const float*)d_in[19];
    const float* r3b  = (const float*)d_in[20];
    const float* convw = (const float*)d_in[21];
    const float* convb = (const float*)d_in[22];
    const int* nodes  = (const int*)d_in[23];
    const int* nbr    = (const int*)d_in[24];
    float* out = (float*)d_out;

    float* ws = (float*)d_ws;
    // float-slot offsets:
    u16*   rxbf   = (u16*)ws;                  // 16,777,216 bf16 (8,388,608 slots)
    float* ub     = ws + 8388608;              // 4,194,304
    float* kernb  = ws + 12582912;             // 2,097,152
    u16*   Qbf    = (u16*)(ws + 14680064);     // 33,554,432 bf16 (16,777,216 slots)
    float* y2b    = ws + 31457280;             // 4,194,304
    u16*   lincbf = (u16*)(ws + 35651584);     // 1,048,576 bf16
    u16*   rincbf = (u16*)(ws + 36175872);     // 2,097,152 bf16
    u16*   gcwbf  = (u16*)(ws + 37224448);     // 524,288 bf16
    float* hpart  = ws;                        // alias rx region (dead by k_h1)
    float* resb   = ws + 4194304;              // still inside rx region

    k_prep<<<3584, 256, 0, stream>>>(linc, rinc, gcw, lincbf, rincbf, gcwbf);
    k_rx  <<<dim3(8, P_, B_), 256, 0, stream>>>(x, rincbf, nbr, rxbf);
    k_u   <<<dim3(P_, B_),    256, 0, stream>>>(x, k3w, nodes, ub);
    k_kern<<<dim3(16, P_, B_),256, 0, stream>>>(linc, ub, rxbf, k4w, ef, k1w, k1b, tin, k2w, k5w, k5b, kernb);
    k_q   <<<dim3(8, P_, B_), 256, 0, stream>>>(rxbf, kernb, gcwbf, Qbf);
    k_y2  <<<dim3(P_, B_),    256, 0, stream>>>(lincbf, Qbf, gcb, y2b);
    k_h1  <<<dim3(64, P_),    256, 0, stream>>>(r0w, y2b, hpart);
    k_wres<<<dim3(P_, B_),    128, 0, stream>>>(hpart, r1w, r1b, r2w, cap, tin, r3w, r3b, y2b, resb);
    k_out <<<B_, 128, 0, stream>>>(convw, convb, resb, out);
}

// Round 3
// 341.050 us; speedup vs baseline: 4.2635x; 2.0873x over previous
//
#include <hip/hip_runtime.h>
#include <math.h>

#define B_ 32
#define N_ 1024
#define F_ 64
#define P_ 8
#define n_ 128
#define m_ 256
#define e_ 1024
#define EF_ 8
#define T_ 16
#define H_ 128
#define W_ 8
#define G_ 128
#define R_ 256
#define L2_ 128

typedef unsigned short u16;
typedef unsigned int u32;
typedef __attribute__((ext_vector_type(8))) short bf16x8;
typedef __attribute__((ext_vector_type(4))) float f32x4;

__device__ __forceinline__ float leakyf(float z, float s) { return z >= 0.f ? z : s * z; }

__device__ __forceinline__ u16 f2bf(float f) {
    u32 u = __float_as_uint(f);
    u += 0x7FFFu + ((u >> 16) & 1u);
    return (u16)(u >> 16);
}
__device__ __forceinline__ float bf2f(u16 h) { return __uint_as_float(((u32)h) << 16); }
__device__ __forceinline__ u32 pk(float a, float b) { return (u32)f2bf(a) | ((u32)f2bf(b) << 16); }

// ---- f32 LDS helpers ----
__device__ __forceinline__ int swz64(int r, int c) {
    return r * 64 + ((((c >> 2) ^ ((r >> 3) & 15)) << 2) | (c & 3));
}
__device__ __forceinline__ float4 ld64(const float* lds, int r, int c4) {
    return *reinterpret_cast<const float4*>(lds + r * 64 + ((c4 ^ ((r >> 3) & 15)) << 2));
}

// ---- bf16 LDS tiles: [rows][64] and [rows][128], chunk-of-8 XOR swizzle ----
__device__ __forceinline__ int swzi(int row, int col) {
    return row * 64 + ((((col >> 3) ^ (row & 7)) << 3) | (col & 7));
}
__device__ __forceinline__ bf16x8 ldfrag(const u16* lds, int row, int kb) {
    return *reinterpret_cast<const bf16x8*>(lds + row * 64 + ((((kb >> 3) ^ (row & 7)) << 3)));
}
__device__ __forceinline__ int swzi128(int row, int col) {
    return row * 128 + ((((col >> 3) ^ (row & 7)) << 3) | (col & 7));
}
__device__ __forceinline__ bf16x8 ldfrag128(const u16* lds, int row, int kb) {
    return *reinterpret_cast<const bf16x8*>(lds + row * 128 + ((((kb >> 3) ^ (row & 7)) << 3)));
}

// ---------------- prep: f32 -> bf16 copies of linc, rinc, gcw ----------------
__global__ __launch_bounds__(256) void k_prep(const float* __restrict__ linc,
                                              const float* __restrict__ rinc,
                                              const float* __restrict__ gcw,
                                              u16* __restrict__ lincbf,
                                              u16* __restrict__ rincbf,
                                              u16* __restrict__ gcwbf) {
    int i = blockIdx.x * 256 + threadIdx.x;
    const float* src;
    u16* dst;
    int base;
    if (i < 262144) { src = linc; dst = lincbf; base = 0; }
    else if (i < 786432) { src = rinc; dst = rincbf; base = 262144; }
    else { src = gcw; dst = gcwbf; base = 786432; }
    int j = i - base;
    float4 v = reinterpret_cast<const float4*>(src)[j];
    ushort4 o = make_ushort4(f2bf(v.x), f2bf(v.y), f2bf(v.z), f2bf(v.w));
    reinterpret_cast<ushort4*>(dst)[j] = o;
}

// ---------------- prep2: lincT, Bw(k4w|k1w|k2w|k1b|0), efbf, k5w tile ----------------
__global__ __launch_bounds__(256) void k_prep2(const float* __restrict__ linc,
                                               const float* __restrict__ k4w,
                                               const float* __restrict__ k1w,
                                               const float* __restrict__ k2w,
                                               const float* __restrict__ k1b,
                                               const float* __restrict__ ef,
                                               const float* __restrict__ k5w,
                                               u16* __restrict__ lincT,
                                               u16* __restrict__ Bw,
                                               u16* __restrict__ efb,
                                               u16* __restrict__ k5wb) {
    const int blk = blockIdx.x, t = threadIdx.x;
    if (blk < 64) {  // transpose linc[p][n][e] tile -> lincT[p][e][n]
        const int p = blk >> 3, et = blk & 7, e0 = et * 128;
        __shared__ u16 S[128 * 128];
        {
            const int nn = t >> 1, seg = (t & 1) * 64;
            const float4* src = reinterpret_cast<const float4*>(
                linc + (size_t)(p * n_ + nn) * e_ + e0 + seg);
#pragma unroll
            for (int q = 0; q < 16; q += 2) {
                float4 a = src[q], b2 = src[q + 1];
                uint4 o = make_uint4(pk(a.x, a.y), pk(a.z, a.w), pk(b2.x, b2.y), pk(b2.z, b2.w));
                int colbase = seg + q * 4;
                int ch = (colbase >> 3) ^ (nn & 7);
                *reinterpret_cast<uint4*>(S + nn * 128 + ch * 8) = o;
            }
        }
        __syncthreads();
        {
            const int e = t >> 1, ns = (t & 1) * 64;
            u16* dst = lincT + ((size_t)(p * e_) + e0 + e) * n_ + ns;
#pragma unroll
            for (int q = 0; q < 8; q++) {
                u16 v[8];
#pragma unroll
                for (int k = 0; k < 8; k++) v[k] = S[swzi128(ns + q * 8 + k, e)];
                uint4 o = make_uint4((u32)v[0] | ((u32)v[1] << 16), (u32)v[2] | ((u32)v[3] << 16),
                                     (u32)v[4] | ((u32)v[5] << 16), (u32)v[6] | ((u32)v[7] << 16));
                *reinterpret_cast<uint4*>(dst + q * 8) = o;
            }
        }
    } else if (blk < 68) {  // Bw[p][h][128] = k4w(64) | k1w(8) | k2w(16) | k1b(1) | 0(39)
        int flat = (blk - 64) * 256 + t;  // p*128+h
        int p = flat >> 7, h = flat & 127;
        u16* dst = Bw + (size_t)flat * 128;
        const float4* s4 = reinterpret_cast<const float4*>(k4w + (size_t)(p * H_ + h) * F_);
#pragma unroll
        for (int q = 0; q < 16; q += 2) {
            float4 a = s4[q], b2 = s4[q + 1];
            *reinterpret_cast<uint4*>(dst + q * 4) =
                make_uint4(pk(a.x, a.y), pk(a.z, a.w), pk(b2.x, b2.y), pk(b2.z, b2.w));
        }
        {
            const float4* s1 = reinterpret_cast<const float4*>(k1w + (size_t)(p * H_ + h) * EF_);
            float4 a = s1[0], b2 = s1[1];
            *reinterpret_cast<uint4*>(dst + 64) =
                make_uint4(pk(a.x, a.y), pk(a.z, a.w), pk(b2.x, b2.y), pk(b2.z, b2.w));
        }
        {
            const float4* s2 = reinterpret_cast<const float4*>(k2w + (size_t)(p * H_ + h) * T_);
#pragma unroll
            for (int q = 0; q < 4; q += 2) {
                float4 a = s2[q], b2 = s2[q + 1];
                *reinterpret_cast<uint4*>(dst + 72 + q * 4) =
                    make_uint4(pk(a.x, a.y), pk(a.z, a.w), pk(b2.x, b2.y), pk(b2.z, b2.w));
            }
        }
        *reinterpret_cast<uint4*>(dst + 88) = make_uint4((u32)f2bf(k1b[p * H_ + h]), 0, 0, 0);
        *reinterpret_cast<uint4*>(dst + 96) = make_uint4(0, 0, 0, 0);
        *reinterpret_cast<uint4*>(dst + 104) = make_uint4(0, 0, 0, 0);
        *reinterpret_cast<uint4*>(dst + 112) = make_uint4(0, 0, 0, 0);
        *reinterpret_cast<uint4*>(dst + 120) = make_uint4(0, 0, 0, 0);
    } else if (blk < 100) {  // efb[p][e][8] from ef[p][e][9] cols 0..8
        int flat = (blk - 68) * 256 + t;  // p*1024+e
        const float* s = ef + (size_t)flat * (EF_ + 1);
        float v0 = s[0], v1 = s[1], v2 = s[2], v3 = s[3], v4 = s[4], v5 = s[5], v6 = s[6], v7 = s[7];
        *reinterpret_cast<uint4*>(efb + (size_t)flat * 8) =
            make_uint4(pk(v0, v1), pk(v2, v3), pk(v4, v5), pk(v6, v7));
    } else {  // k5wb[p][16][128], pre-swizzled, rows 8..15 zero
        int p = blk - 100;
        int row = t >> 4, col8 = (t & 15) * 8;
        uint4 o = make_uint4(0, 0, 0, 0);
        if (row < 8) {
            const float4* s = reinterpret_cast<const float4*>(k5w + (size_t)(p * W_ + row) * H_ + col8);
            float4 a = s[0], b2 = s[1];
            o = make_uint4(pk(a.x, a.y), pk(a.z, a.w), pk(b2.x, b2.y), pk(b2.z, b2.w));
        }
        int ch = (col8 >> 3) ^ (row & 7);
        *reinterpret_cast<uint4*>(k5wb + (size_t)p * 2048 + row * 128 + ch * 8) = o;
    }
}

// ---------------- K1 (MFMA): rx[b,p,e,f] = sum_m rinc[p,e,m] * x[b,nbr[p,m],f] ----------------
__global__ __launch_bounds__(256) void k_rx(const float* __restrict__ x,
                                            const u16* __restrict__ rincbf,
                                            const int* __restrict__ nbr,
                                            u16* __restrict__ rxbf) {
    const int et = blockIdx.x, p = blockIdx.y, b = blockIdx.z;
    const int t = threadIdx.x, lane = t & 63, wid = t >> 6;
    __shared__ __align__(16) u16 A_lds[128 * 64];
    __shared__ __align__(16) u16 BT_lds[64 * 64];
    f32x4 acc[2][4];
#pragma unroll
    for (int i = 0; i < 2; i++)
#pragma unroll
        for (int j = 0; j < 4; j++) acc[i][j] = 0.f;

    const int e0 = et * 128;
    for (int c = 0; c < 4; c++) {
        const int m0 = c * 64;
        __syncthreads();
        {
            int ee = t >> 1, seg = t & 1;
            const uint4* src = reinterpret_cast<const uint4*>(
                rincbf + ((size_t)(p * e_ + e0 + ee) * m_ + m0 + seg * 32));
#pragma unroll
            for (int q = 0; q < 4; q++) {
                uint4 v = src[q];
                int ch = (seg * 4 + q) ^ (ee & 7);
                *reinterpret_cast<uint4*>(A_lds + ee * 64 + ch * 8) = v;
            }
        }
        {
            int mm = t >> 2, fq = (t & 3) * 16;
            int row = nbr[p * m_ + m0 + mm];
            const float4* sx = reinterpret_cast<const float4*>(
                x + (size_t)(b * N_ + row) * F_ + fq);
#pragma unroll
            for (int q = 0; q < 4; q++) {
                float4 v = sx[q];
                int f0 = fq + q * 4;
                BT_lds[swzi(f0 + 0, mm)] = f2bf(v.x);
                BT_lds[swzi(f0 + 1, mm)] = f2bf(v.y);
                BT_lds[swzi(f0 + 2, mm)] = f2bf(v.z);
                BT_lds[swzi(f0 + 3, mm)] = f2bf(v.w);
            }
        }
        __syncthreads();
        const int wm0 = wid * 32, r15 = lane & 15, g4 = lane >> 4;
#pragma unroll
        for (int ks = 0; ks < 2; ks++) {
            int kb = ks * 32 + g4 * 8;
            bf16x8 af[2], bfr[4];
#pragma unroll
            for (int mf = 0; mf < 2; mf++) af[mf] = ldfrag(A_lds, wm0 + mf * 16 + r15, kb);
#pragma unroll
            for (int nf = 0; nf < 4; nf++) bfr[nf] = ldfrag(BT_lds, nf * 16 + r15, kb);
#pragma unroll
            for (int mf = 0; mf < 2; mf++)
#pragma unroll
                for (int nf = 0; nf < 4; nf++)
                    acc[mf][nf] = __builtin_amdgcn_mfma_f32_16x16x32_bf16(af[mf], bfr[nf], acc[mf][nf], 0, 0, 0);
        }
    }
    const int r15 = lane & 15, g4 = lane >> 4;
#pragma unroll
    for (int mf = 0; mf < 2; mf++)
#pragma unroll
        for (int nf = 0; nf < 4; nf++)
#pragma unroll
            for (int r = 0; r < 4; r++) {
                int erow = e0 + wid * 32 + mf * 16 + g4 * 4 + r;
                int f = nf * 16 + r15;
                rxbf[((size_t)(b * P_ + p) * e_ + erow) * F_ + f] = f2bf(acc[mf][nf][r]);
            }
}

// ---------------- K2: uT[b,p,h,n] (bf16) = sum_f k3_w[p,h,f] * x[b,nodes[p,n],f] ----------------
__global__ __launch_bounds__(256) void k_u(const float* __restrict__ x,
                                           const float* __restrict__ k3w,
                                           const int* __restrict__ nodes,
                                           u16* __restrict__ uT) {
    const int p = blockIdx.x, b = blockIdx.y;
    const int t = threadIdx.x;
    const int th = t & 15;
    const int tn = t >> 4;
    __shared__ float xg[128 * 64];
    __shared__ float kw[128 * 64];
    for (int idx = t; idx < 8192; idx += 256) {
        int r = idx >> 6, f = idx & 63;
        int row = nodes[p * n_ + r];
        xg[swz64(r, f)] = x[(size_t)(b * N_ + row) * F_ + f];
        kw[swz64(r, f)] = k3w[(size_t)(p * H_ + r) * F_ + f];
    }
    __syncthreads();
    float acc[8][8];
#pragma unroll
    for (int i = 0; i < 8; i++)
#pragma unroll
        for (int j = 0; j < 8; j++) acc[i][j] = 0.f;
#pragma unroll 2
    for (int k4 = 0; k4 < 16; k4++) {
        float4 xv[8];
#pragma unroll
        for (int i = 0; i < 8; i++) xv[i] = ld64(xg, tn * 8 + i, k4);
#pragma unroll
        for (int j = 0; j < 8; j++) {
            float4 kv = ld64(kw, th * 8 + j, k4);
#pragma unroll
            for (int i = 0; i < 8; i++) {
                acc[i][j] += xv[i].x * kv.x + xv[i].y * kv.y + xv[i].z * kv.z + xv[i].w * kv.w;
            }
        }
    }
    // write transposed bf16: uT[h][n]
#pragma unroll
    for (int j = 0; j < 8; j++) {
        uint4 o = make_uint4(pk(acc[0][j], acc[1][j]), pk(acc[2][j], acc[3][j]),
                             pk(acc[4][j], acc[5][j]), pk(acc[6][j], acc[7][j]));
        *reinterpret_cast<uint4*>(uT + ((size_t)(b * P_ + p) * H_ + th * 8 + j) * n_ + tn * 8) = o;
    }
}

// ---------------- K3 (MFMA): kernel[b,p,e,w] ----------------
// k[e,h] = sum_K A[e,K]*B[h,K], K=256: [0,128)=n via lincT/uT, [128,192)=f via rx/k4w,
// [192,200)=ef/k1w, [200,216)=t/k2w, 216=1/k1b, rest 0.
// then kernel[e,w] = relu(sum_h k5w[w,h]*leaky(k[e,h]) + k5b[w]) via second MFMA.
__global__ __launch_bounds__(256) void k_kern(const u16* __restrict__ lincT,
                                              const u16* __restrict__ uT,
                                              const u16* __restrict__ rxbf,
                                              const u16* __restrict__ Bw,
                                              const u16* __restrict__ efb,
                                              const float* __restrict__ tin,
                                              const u16* __restrict__ k5wb,
                                              const float* __restrict__ k5b,
                                              float* __restrict__ kern) {
    const int et = blockIdx.x, p = blockIdx.y, b = blockIdx.z;
    const int t = threadIdx.x, lane = t & 63, wid = t >> 6;
    const int r15 = lane & 15, g4 = lane >> 4;
    const int wm = (wid >> 1) * 64, wn = (wid & 1) * 64;
    __shared__ __align__(16) u16 S[128 * 128 + 16 * 128];  // A=[0,8192) B=[8192,16384) k5=[16384,18432)
    u16* A_lds = S;
    u16* B_lds = S + 8192;
    u16* k5l = S + 16384;

    // stage k5 tile (pre-swizzled in prep)
    {
        uint4 v = reinterpret_cast<const uint4*>(k5wb + (size_t)p * 2048)[t];
        reinterpret_cast<uint4*>(k5l)[t] = v;
    }
    // tin packed (broadcast loads)
    uint4 tinlo, tinhi;
    {
        const float4* s = reinterpret_cast<const float4*>(tin + b * T_);
        float4 a = s[0], b2 = s[1], c2 = s[2], d2 = s[3];
        tinlo = make_uint4(pk(a.x, a.y), pk(a.z, a.w), pk(b2.x, b2.y), pk(b2.z, b2.w));
        tinhi = make_uint4(pk(c2.x, c2.y), pk(c2.z, c2.w), pk(d2.x, d2.y), pk(d2.z, d2.w));
    }

    f32x4 acc[4][4];
#pragma unroll
    for (int i = 0; i < 4; i++)
#pragma unroll
        for (int j = 0; j < 4; j++) acc[i][j] = 0.f;

    const int e0 = et * 128;
    const size_t pb_e = (size_t)(b * P_ + p) * e_;
    const int row = t >> 1, half = t & 1;

    for (int c = 0; c < 4; c++) {
        __syncthreads();
        // ---- stage A rows (e-local) ----
        if (c < 2) {
            const uint4* src = reinterpret_cast<const uint4*>(
                lincT + ((size_t)(p * e_) + e0 + row) * n_ + c * 64 + half * 32);
#pragma unroll
            for (int q = 0; q < 4; q++) {
                uint4 v = src[q];
                int ch = (half * 4 + q) ^ (row & 7);
                *reinterpret_cast<uint4*>(A_lds + row * 64 + ch * 8) = v;
            }
        } else if (c == 2) {
            const uint4* src = reinterpret_cast<const uint4*>(
                rxbf + (pb_e + e0 + row) * F_ + half * 32);
#pragma unroll
            for (int q = 0; q < 4; q++) {
                uint4 v = src[q];
                int ch = (half * 4 + q) ^ (row & 7);
                *reinterpret_cast<uint4*>(A_lds + row * 64 + ch * 8) = v;
            }
        } else {
            uint4 w[4];
            if (half == 0) {
                w[0] = *reinterpret_cast<const uint4*>(efb + ((size_t)(p * e_) + e0 + row) * 8);
                w[1] = tinlo;
                w[2] = tinhi;
                w[3] = make_uint4(0x00003F80u, 0, 0, 0);  // bf16 1.0 at col 24
            } else {
                w[0] = w[1] = w[2] = w[3] = make_uint4(0, 0, 0, 0);
            }
#pragma unroll
            for (int q = 0; q < 4; q++) {
                int ch = (half * 4 + q) ^ (row & 7);
                *reinterpret_cast<uint4*>(A_lds + row * 64 + ch * 8) = w[q];
            }
        }
        // ---- stage B rows (h) ----
        {
            const uint4* src;
            if (c < 2)
                src = reinterpret_cast<const uint4*>(
                    uT + ((size_t)(b * P_ + p) * H_ + row) * n_ + c * 64 + half * 32);
            else
                src = reinterpret_cast<const uint4*>(
                    Bw + (size_t)(p * H_ + row) * 128 + (c - 2) * 64 + half * 32);
#pragma unroll
            for (int q = 0; q < 4; q++) {
                uint4 v = src[q];
                int ch = (half * 4 + q) ^ (row & 7);
                *reinterpret_cast<uint4*>(B_lds + row * 64 + ch * 8) = v;
            }
        }
        __syncthreads();
#pragma unroll
        for (int ks = 0; ks < 2; ks++) {
            int kb = ks * 32 + g4 * 8;
            bf16x8 af[4], bfr[4];
#pragma unroll
            for (int mf = 0; mf < 4; mf++) af[mf] = ldfrag(A_lds, wm + mf * 16 + r15, kb);
#pragma unroll
            for (int nf = 0; nf < 4; nf++) bfr[nf] = ldfrag(B_lds, wn + nf * 16 + r15, kb);
#pragma unroll
            for (int mf = 0; mf < 4; mf++)
#pragma unroll
                for (int nf = 0; nf < 4; nf++)
                    acc[mf][nf] = __builtin_amdgcn_mfma_f32_16x16x32_bf16(af[mf], bfr[nf], acc[mf][nf], 0, 0, 0);
        }
    }
    // ---- epilogue: leaky(k) -> bf16 LDS [128e][128h], then MFMA with k5 tile ----
    __syncthreads();
    u16* Kl = S;  // reuse A+B area: 128*128
#pragma unroll
    for (int mf = 0; mf < 4; mf++)
#pragma unroll
        for (int nf = 0; nf < 4; nf++)
#pragma unroll
            for (int r = 0; r < 4; r++) {
                int er = wm + mf * 16 + g4 * 4 + r;
                int hc = wn + nf * 16 + r15;
                Kl[swzi128(er, hc)] = f2bf(leakyf(acc[mf][nf][r], 0.02f));
            }
    __syncthreads();
    f32x4 acc2[2];
    acc2[0] = 0.f;
    acc2[1] = 0.f;
#pragma unroll
    for (int ks = 0; ks < 4; ks++) {
        int kb = ks * 32 + g4 * 8;
        bf16x8 bf5 = ldfrag128(k5l, r15, kb);
#pragma unroll
        for (int mf2 = 0; mf2 < 2; mf2++) {
            bf16x8 af = ldfrag128(Kl, wid * 32 + mf2 * 16 + r15, kb);
            acc2[mf2] = __builtin_amdgcn_mfma_f32_16x16x32_bf16(af, bf5, acc2[mf2], 0, 0, 0);
        }
    }
    if (r15 < 8) {
        float kb5 = k5b[p * W_ + r15];
#pragma unroll
        for (int mf2 = 0; mf2 < 2; mf2++)
#pragma unroll
            for (int r = 0; r < 4; r++) {
                int er = e0 + wid * 32 + mf2 * 16 + g4 * 4 + r;
                kern[(pb_e + er) * W_ + r15] = fmaxf(acc2[mf2][r] + kb5, 0.f);
            }
    }
}

// ---------------- K4 (MFMA): Q[b,p,e,g] = sum_{w,f} (kern[e,w]*rx[e,f]) * gcw[g,w*F+f] ----------------
__global__ __launch_bounds__(256) void k_q(const u16* __restrict__ rxbf,
                                           const float* __restrict__ kernb,
                                           const u16* __restrict__ gcwbf,
                                           u16* __restrict__ Qbf) {
    const int et = blockIdx.x, p = blockIdx.y, b = blockIdx.z;
    const int t = threadIdx.x, lane = t & 63, wid = t >> 6;
    __shared__ __align__(16) u16 A_lds[128 * 64];
    __shared__ __align__(16) u16 BT_lds[128 * 64];
    f32x4 acc[4][4];
#pragma unroll
    for (int i = 0; i < 4; i++)
#pragma unroll
        for (int j = 0; j < 4; j++) acc[i][j] = 0.f;

    const int e0 = et * 128;
    const size_t pb_e = (size_t)(b * P_ + p) * e_;
    const int wm = (wid >> 1) * 64, wn = (wid & 1) * 64;
    const int r15 = lane & 15, g4 = lane >> 4;

    for (int w = 0; w < 8; w++) {
        __syncthreads();
        {
            int ee = t >> 1, seg = t & 1;
            float ksc = kernb[(pb_e + e0 + ee) * W_ + w];
            const uint4* src = reinterpret_cast<const uint4*>(rxbf + (pb_e + e0 + ee) * F_ + seg * 32);
#pragma unroll
            for (int q = 0; q < 4; q++) {
                uint4 v = src[q];
                u32 vv[4] = {v.x, v.y, v.z, v.w};
                u32 ov[4];
#pragma unroll
                for (int q2 = 0; q2 < 4; q2++) {
                    float f0 = bf2f((u16)(vv[q2] & 0xFFFF)) * ksc;
                    float f1 = bf2f((u16)(vv[q2] >> 16)) * ksc;
                    ov[q2] = (u32)f2bf(f0) | ((u32)f2bf(f1) << 16);
                }
                int ch = (seg * 4 + q) ^ (ee & 7);
                *reinterpret_cast<uint4*>(A_lds + ee * 64 + ch * 8) =
                    make_uint4(ov[0], ov[1], ov[2], ov[3]);
            }
        }
        {
            int gg = t >> 1, seg = t & 1;
            const uint4* src = reinterpret_cast<const uint4*>(
                gcwbf + (size_t)(p * G_ + gg) * 512 + w * 64 + seg * 32);
#pragma unroll
            for (int q = 0; q < 4; q++) {
                uint4 v = src[q];
                int ch = (seg * 4 + q) ^ (gg & 7);
                *reinterpret_cast<uint4*>(BT_lds + gg * 64 + ch * 8) = v;
            }
        }
        __syncthreads();
#pragma unroll
        for (int ks = 0; ks < 2; ks++) {
            int kb = ks * 32 + g4 * 8;
            bf16x8 af[4], bfr[4];
#pragma unroll
            for (int mf = 0; mf < 4; mf++) af[mf] = ldfrag(A_lds, wm + mf * 16 + r15, kb);
#pragma unroll
            for (int nf = 0; nf < 4; nf++) bfr[nf] = ldfrag(BT_lds, wn + nf * 16 + r15, kb);
#pragma unroll
            for (int mf = 0; mf < 4; mf++)
#pragma unroll
                for (int nf = 0; nf < 4; nf++)
                    acc[mf][nf] = __builtin_amdgcn_mfma_f32_16x16x32_bf16(af[mf], bfr[nf], acc[mf][nf], 0, 0, 0);
        }
    }
#pragma unroll
    for (int mf = 0; mf < 4; mf++)
#pragma unroll
        for (int nf = 0; nf < 4; nf++)
#pragma unroll
            for (int r = 0; r < 4; r++) {
                int erow = e0 + wm + mf * 16 + g4 * 4 + r;
                int g = wn + nf * 16 + r15;
                Qbf[(pb_e + erow) * G_ + g] = f2bf(acc[mf][nf][r]);
            }
}

// ---------------- K5 (MFMA): y2[b,p,n,g] = relu(sum_e linc[n,e]*Q[e,g] + gcb[g]) ----------------
__global__ __launch_bounds__(256) void k_y2(const u16* __restrict__ lincbf,
                                            const u16* __restrict__ Qbf,
                                            const float* __restrict__ gcb,
                                            float* __restrict__ y2) {
    const int p = blockIdx.x, b = blockIdx.y;
    const int t = threadIdx.x, lane = t & 63, wid = t >> 6;
    __shared__ __align__(16) u16 A_lds[128 * 64];
    __shared__ __align__(16) u16 BT_lds[128 * 64];
    f32x4 acc[4][4];
#pragma unroll
    for (int i = 0; i < 4; i++)
#pragma unroll
        for (int j = 0; j < 4; j++) acc[i][j] = 0.f;

    const size_t pb_e = (size_t)(b * P_ + p) * e_;
    const int wm = (wid >> 1) * 64, wn = (wid & 1) * 64;
    const int r15 = lane & 15, g4 = lane >> 4;

    for (int c = 0; c < 16; c++) {
        const int e0 = c * 64;
        __syncthreads();
        {
            int nn = t >> 1, seg = t & 1;
            const uint4* src = reinterpret_cast<const uint4*>(
                lincbf + (size_t)(p * n_ + nn) * e_ + e0 + seg * 32);
#pragma unroll
            for (int q = 0; q < 4; q++) {
                uint4 v = src[q];
                int ch = (seg * 4 + q) ^ (nn & 7);
                *reinterpret_cast<uint4*>(A_lds + nn * 64 + ch * 8) = v;
            }
        }
        {
            int ek = t >> 2, gq = (t & 3) * 32;
            const uint4* src = reinterpret_cast<const uint4*>(Qbf + (pb_e + e0 + ek) * G_ + gq);
#pragma unroll
            for (int q = 0; q < 4; q++) {
                uint4 v = src[q];
                u32 vv[4] = {v.x, v.y, v.z, v.w};
#pragma unroll
                for (int q2 = 0; q2 < 4; q2++) {
                    int g0 = gq + q * 8 + q2 * 2;
                    BT_lds[swzi(g0, ek)] = (u16)(vv[q2] & 0xFFFF);
                    BT_lds[swzi(g0 + 1, ek)] = (u16)(vv[q2] >> 16);
                }
            }
        }
        __syncthreads();
#pragma unroll
        for (int ks = 0; ks < 2; ks++) {
            int kb = ks * 32 + g4 * 8;
            bf16x8 af[4], bfr[4];
#pragma unroll
            for (int mf = 0; mf < 4; mf++) af[mf] = ldfrag(A_lds, wm + mf * 16 + r15, kb);
#pragma unroll
            for (int nf = 0; nf < 4; nf++) bfr[nf] = ldfrag(BT_lds, wn + nf * 16 + r15, kb);
#pragma unroll
            for (int mf = 0; mf < 4; mf++)
#pragma unroll
                for (int nf = 0; nf < 4; nf++)
                    acc[mf][nf] = __builtin_amdgcn_mfma_f32_16x16x32_bf16(af[mf], bfr[nf], acc[mf][nf], 0, 0, 0);
        }
    }
#pragma unroll
    for (int mf = 0; mf < 4; mf++)
#pragma unroll
        for (int nf = 0; nf < 4; nf++) {
            int g = wn + nf * 16 + r15;
            float gb = gcb[p * G_ + g];
#pragma unroll
            for (int r = 0; r < 4; r++) {
                int nrow = wm + mf * 16 + g4 * 4 + r;
                y2[((size_t)(b * P_ + p) * n_ + nrow) * G_ + g] = fmaxf(acc[mf][nf][r] + gb, 0.f);
            }
        }
}

// ---------------- K6: hpart[ks,p,r,b] = sum_{k in slice} r0_w[p,r,k]*y2flat[b,p,k] ----------------
__global__ __launch_bounds__(256) void k_h1(const float* __restrict__ r0w,
                                            const float* __restrict__ y2,
                                            float* __restrict__ hpart) {
    const int ks = blockIdx.x;
    const int p = blockIdx.y;
    const int t = threadIdx.x;
    const int bg = t & 7;
    const int rg = t >> 3;
    __shared__ float yl[32 * 256];
    const int kc = ks * 256;
    for (int idx = t; idx < 8192; idx += 256) {
        int bb = idx >> 8, kk = idx & 255;
        yl[bb * 256 + ((((kk >> 2) ^ ((bb >> 2) & 7)) << 2) | (kk & 3))] =
            y2[(size_t)(bb * P_ + p) * (n_ * G_) + kc + kk];
    }
    __syncthreads();
    float acc[8][4];
#pragma unroll
    for (int i = 0; i < 8; i++)
#pragma unroll
        for (int j = 0; j < 4; j++) acc[i][j] = 0.f;

    for (int run = 0; run < 16; run++) {
        float4 y2v[4][4];
#pragma unroll
        for (int j = 0; j < 4; j++) {
            int bb = bg * 4 + j;
            int sw = (bb >> 2) & 7;
#pragma unroll
            for (int q = 0; q < 4; q++) {
                int c4 = (run * 4 + q) ^ sw;
                y2v[j][q] = *reinterpret_cast<const float4*>(yl + bb * 256 + (c4 << 2));
            }
        }
#pragma unroll
        for (int i = 0; i < 8; i++) {
            int r = rg * 8 + i;
            const float4* r0p =
                reinterpret_cast<const float4*>(r0w + (size_t)(p * R_ + r) * 16384 + kc + run * 16);
            float4 r0v[4];
#pragma unroll
            for (int q = 0; q < 4; q++) r0v[q] = r0p[q];
#pragma unroll
            for (int j = 0; j < 4; j++) {
#pragma unroll
                for (int q = 0; q < 4; q++) {
                    acc[i][j] += r0v[q].x * y2v[j][q].x + r0v[q].y * y2v[j][q].y +
                                 r0v[q].z * y2v[j][q].z + r0v[q].w * y2v[j][q].w;
                }
            }
        }
    }
#pragma unroll
    for (int i = 0; i < 8; i++) {
        size_t off = ((size_t)(ks * P_ + p) * R_ + rg * 8 + i) * 32 + bg * 4;
        *reinterpret_cast<float4*>(hpart + off) = make_float4(acc[i][0], acc[i][1], acc[i][2], acc[i][3]);
    }
}

// ---------------- K7: h -> leaky -> w -> res ----------------
__global__ __launch_bounds__(128) void k_wres(const float* __restrict__ hpart,
                                              const float* __restrict__ r1w,
                                              const float* __restrict__ r1b,
                                              const float* __restrict__ r2w,
                                              const float* __restrict__ cap,
                                              const float* __restrict__ tin,
                                              const float* __restrict__ r3w,
                                              const float* __restrict__ r3b,
                                              const float* __restrict__ y2,
                                              float* __restrict__ res) {
    const int p = blockIdx.x, b = blockIdx.y;
    const int t = threadIdx.x;
    __shared__ float lh[256];
    __shared__ float wl[128];
    for (int rr = t; rr < 256; rr += 128) {
        float s = 0.f;
        for (int ks = 0; ks < 64; ks++) s += hpart[((size_t)(ks * P_ + p) * R_ + rr) * 32 + b];
        for (int tt = 0; tt < T_; tt++) s += r1w[(size_t)(p * R_ + rr) * T_ + tt] * tin[b * T_ + tt];
        s += r1b[p * R_ + rr];
        for (int nn = 0; nn < n_; nn++) s += r2w[(size_t)(p * R_ + rr) * n_ + nn] * cap[p * n_ + nn];
        lh[rr] = leakyf(s, 0.01f);
    }
    __syncthreads();
    {
        const int nn = t;
        float accw = r3b[p * n_ + nn];
        const float* r3p = r3w + (size_t)(p * n_ + nn) * R_;
        for (int r = 0; r < 256; r += 4) {
            float4 rv = *reinterpret_cast<const float4*>(r3p + r);
            accw += rv.x * lh[r] + rv.y * lh[r + 1] + rv.z * lh[r + 2] + rv.w * lh[r + 3];
        }
        wl[nn] = fmaxf(accw, 0.f);
    }
    __syncthreads();
    {
        const int g = t;
        float a = 0.f;
        for (int nn = 0; nn < n_; nn++) a += wl[nn] * y2[((size_t)(b * P_ + p) * n_ + nn) * G_ + g];
        res[(b * P_ + p) * G_ + g] = a;
    }
}

// ---------------- K8: out[b,l] ----------------
__global__ __launch_bounds__(128) void k_out(const float* __restrict__ convw,
                                             const float* __restrict__ convb,
                                             const float* __restrict__ res,
                                             float* __restrict__ out) {
    const int b = blockIdx.x;
    const int t = threadIdx.x;
    __shared__ float rl[1024];
    for (int idx = t; idx < 1024; idx += 128) rl[idx] = res[b * 1024 + idx];
    __syncthreads();
    float a = convb[t];
    const float* cw = convw + (size_t)t * 1024;
    for (int gp = 0; gp < 1024; gp += 4) {
        float4 v = *reinterpret_cast<const float4*>(cw + gp);
        a += v.x * rl[((gp + 0) & 7) * 128 + ((gp + 0) >> 3)];
        a += v.y * rl[((gp + 1) & 7) * 128 + ((gp + 1) >> 3)];
        a += v.z * rl[((gp + 2) & 7) * 128 + ((gp + 2) >> 3)];
        a += v.w * rl[((gp + 3) & 7) * 128 + ((gp + 3) >> 3)];
    }
    out[b * L2_ + t] = leakyf(a, 0.02f);
}

extern "C" void kernel_launch(void* const* d_in, const int* in_sizes, int n_in,
                              void* d_out, int out_size, void* d_ws, size_t ws_size,
                              hipStream_t stream) {
    const float* x    = (const float*)d_in[0];
    const float* tin  = (const float*)d_in[1];
    const float* ef   = (const float*)d_in[2];
    const float* linc = (const float*)d_in[3];
    const float* rinc = (const float*)d_in[4];
    const float* cap  = (const float*)d_in[5];
    const float* k1w  = (const float*)d_in[6];
    const float* k1b  = (const float*)d_in[7];
    const float* k2w  = (const float*)d_in[8];
    const float* k3w  = (const float*)d_in[9];
    const float* k4w  = (const float*)d_in[10];
    const float* k5w  = (const float*)d_in[11];
    const float* k5b  = (const float*)d_in[12];
    const float* gcw  = (const float*)d_in[13];
    const float* gcb  = (const float*)d_in[14];
    const float* r0w  = (const float*)d_in[15];
    const float* r1w  = (const float*)d_in[16];
    const float* r1b  = (const float*)d_in[17];
    const float* r2w  = (const float*)d_in[18];
    const float* r3w  = (const float*)d_in[19];
    const float* r3b  = (const float*)d_in[20];
    const float* convw = (const float*)d_in[21];
    const float* convb = (const float*)d_in[22];
    const int* nodes  = (const int*)d_in[23];
    const int* nbr    = (const int*)d_in[24];
    float* out = (float*)d_out;

    float* ws = (float*)d_ws;
    u16*   rxbf   = (u16*)ws;                  // [0, 8388608) f-slots
    u16*   uTbf   = (u16*)(ws + 8388608);      // [8388608, 10485760)
    float* kernb  = ws + 10485760;             // [10485760, 12582912)
    u16*   Qbf    = (u16*)(ws + 12582912);     // [12582912, 29360128)
    float* y2b    = ws + 29360128;             // [29360128, 33554432)
    u16*   lincbf = (u16*)(ws + 33554432);     // 524288 slots
    u16*   lincT  = (u16*)(ws + 34078720);     // 524288
    u16*   rincbf = (u16*)(ws + 34603008);     // 1048576
    u16*   gcwbf  = (u16*)(ws + 35651584);     // 262144
    u16*   Bwbf   = (u16*)(ws + 35913728);     // 65536
    u16*   efbf   = (u16*)(ws + 35979264);     // 32768
    u16*   k5wbf  = (u16*)(ws + 36012032);     // 8192
    float* hpart  = ws;                        // alias rx region (dead after k_q)
    float* resb   = ws + 4194304;

    k_prep <<<3584, 256, 0, stream>>>(linc, rinc, gcw, lincbf, rincbf, gcwbf);
    k_prep2<<<108, 256, 0, stream>>>(linc, k4w, k1w, k2w, k1b, ef, k5w, lincT, Bwbf, efbf, k5wbf);
    k_rx  <<<dim3(8, P_, B_), 256, 0, stream>>>(x, rincbf, nbr, rxbf);
    k_u   <<<dim3(P_, B_),    256, 0, stream>>>(x, k3w, nodes, uTbf);
    k_kern<<<dim3(8, P_, B_), 256, 0, stream>>>(lincT, uTbf, rxbf, Bwbf, efbf, tin, k5wbf, k5b, kernb);
    k_q   <<<dim3(8, P_, B_), 256, 0, stream>>>(rxbf, kernb, gcwbf, Qbf);
    k_y2  <<<dim3(P_, B_),    256, 0, stream>>>(lincbf, Qbf, gcb, y2b);
    k_h1  <<<dim3(64, P_),    256, 0, stream>>>(r0w, y2b, hpart);
    k_wres<<<dim3(P_, B_),    128, 0, stream>>>(hpart, r1w, r1b, r2w, cap, tin, r3w, r3b, y2b, resb);
    k_out <<<B_, 128, 0, stream>>>(convw, convb, resb, out);
}

// Round 4
// 329.193 us; speedup vs baseline: 4.4170x; 1.0360x over previous
//
#include <hip/hip_runtime.h>
#include <math.h>

#define B_ 32
#define N_ 1024
#define F_ 64
#define P_ 8
#define n_ 128
#define m_ 256
#define e_ 1024
#define EF_ 8
#define T_ 16
#define H_ 128
#define W_ 8
#define G_ 128
#define R_ 256
#define L2_ 128

typedef unsigned short u16;
typedef unsigned int u32;
typedef __attribute__((ext_vector_type(8))) short bf16x8;
typedef __attribute__((ext_vector_type(4))) float f32x4;

__device__ __forceinline__ float leakyf(float z, float s) { return z >= 0.f ? z : s * z; }

__device__ __forceinline__ u16 f2bf(float f) {
    u32 u = __float_as_uint(f);
    u += 0x7FFFu + ((u >> 16) & 1u);
    return (u16)(u >> 16);
}
__device__ __forceinline__ float bf2f(u16 h) { return __uint_as_float(((u32)h) << 16); }
__device__ __forceinline__ u32 pk(float a, float b) { return (u32)f2bf(a) | ((u32)f2bf(b) << 16); }

// ---- f32 LDS helpers ----
__device__ __forceinline__ int swz64(int r, int c) {
    return r * 64 + ((((c >> 2) ^ ((r >> 3) & 15)) << 2) | (c & 3));
}
__device__ __forceinline__ float4 ld64(const float* lds, int r, int c4) {
    return *reinterpret_cast<const float4*>(lds + r * 64 + ((c4 ^ ((r >> 3) & 15)) << 2));
}

// ---- bf16 LDS tiles: [rows][64] and [rows][128], chunk-of-8 XOR swizzle ----
__device__ __forceinline__ int swzi(int row, int col) {
    return row * 64 + ((((col >> 3) ^ (row & 7)) << 3) | (col & 7));
}
__device__ __forceinline__ bf16x8 ldfrag(const u16* lds, int row, int kb) {
    return *reinterpret_cast<const bf16x8*>(lds + row * 64 + ((((kb >> 3) ^ (row & 7)) << 3)));
}
__device__ __forceinline__ int swzi128(int row, int col) {
    return row * 128 + ((((col >> 3) ^ (row & 7)) << 3) | (col & 7));
}
__device__ __forceinline__ bf16x8 ldfrag128(const u16* lds, int row, int kb) {
    return *reinterpret_cast<const bf16x8*>(lds + row * 128 + ((((kb >> 3) ^ (row & 7)) << 3)));
}

// ---------------- prep: f32 -> bf16 copies of linc, rinc, gcw ----------------
__global__ __launch_bounds__(256) void k_prep(const float* __restrict__ linc,
                                              const float* __restrict__ rinc,
                                              const float* __restrict__ gcw,
                                              u16* __restrict__ lincbf,
                                              u16* __restrict__ rincbf,
                                              u16* __restrict__ gcwbf) {
    int i = blockIdx.x * 256 + threadIdx.x;
    const float* src;
    u16* dst;
    int base;
    if (i < 262144) { src = linc; dst = lincbf; base = 0; }
    else if (i < 786432) { src = rinc; dst = rincbf; base = 262144; }
    else { src = gcw; dst = gcwbf; base = 786432; }
    int j = i - base;
    float4 v = reinterpret_cast<const float4*>(src)[j];
    ushort4 o = make_ushort4(f2bf(v.x), f2bf(v.y), f2bf(v.z), f2bf(v.w));
    reinterpret_cast<ushort4*>(dst)[j] = o;
}

// ---------------- prep2: lincT, Bw(k4w|k1w|k2w|k1b|0), efbf, k5w tile ----------------
__global__ __launch_bounds__(256) void k_prep2(const float* __restrict__ linc,
                                               const float* __restrict__ k4w,
                                               const float* __restrict__ k1w,
                                               const float* __restrict__ k2w,
                                               const float* __restrict__ k1b,
                                               const float* __restrict__ ef,
                                               const float* __restrict__ k5w,
                                               u16* __restrict__ lincT,
                                               u16* __restrict__ Bw,
                                               u16* __restrict__ efb,
                                               u16* __restrict__ k5wb) {
    const int blk = blockIdx.x, t = threadIdx.x;
    if (blk < 64) {  // transpose linc[p][n][e] tile -> lincT[p][e][n]
        const int p = blk >> 3, et = blk & 7, e0 = et * 128;
        __shared__ u16 S[128 * 128];
        {
            const int nn = t >> 1, seg = (t & 1) * 64;
            const float4* src = reinterpret_cast<const float4*>(
                linc + (size_t)(p * n_ + nn) * e_ + e0 + seg);
#pragma unroll
            for (int q = 0; q < 16; q += 2) {
                float4 a = src[q], b2 = src[q + 1];
                uint4 o = make_uint4(pk(a.x, a.y), pk(a.z, a.w), pk(b2.x, b2.y), pk(b2.z, b2.w));
                int colbase = seg + q * 4;
                int ch = (colbase >> 3) ^ (nn & 7);
                *reinterpret_cast<uint4*>(S + nn * 128 + ch * 8) = o;
            }
        }
        __syncthreads();
        {
            const int e = t >> 1, ns = (t & 1) * 64;
            u16* dst = lincT + ((size_t)(p * e_) + e0 + e) * n_ + ns;
#pragma unroll
            for (int q = 0; q < 8; q++) {
                u16 v[8];
#pragma unroll
                for (int k = 0; k < 8; k++) v[k] = S[swzi128(ns + q * 8 + k, e)];
                uint4 o = make_uint4((u32)v[0] | ((u32)v[1] << 16), (u32)v[2] | ((u32)v[3] << 16),
                                     (u32)v[4] | ((u32)v[5] << 16), (u32)v[6] | ((u32)v[7] << 16));
                *reinterpret_cast<uint4*>(dst + q * 8) = o;
            }
        }
    } else if (blk < 68) {  // Bw[p][h][128] = k4w(64) | k1w(8) | k2w(16) | k1b(1) | 0(39)
        int flat = (blk - 64) * 256 + t;  // p*128+h
        int p = flat >> 7, h = flat & 127;
        u16* dst = Bw + (size_t)flat * 128;
        const float4* s4 = reinterpret_cast<const float4*>(k4w + (size_t)(p * H_ + h) * F_);
#pragma unroll
        for (int q = 0; q < 16; q += 2) {
            float4 a = s4[q], b2 = s4[q + 1];
            *reinterpret_cast<uint4*>(dst + q * 4) =
                make_uint4(pk(a.x, a.y), pk(a.z, a.w), pk(b2.x, b2.y), pk(b2.z, b2.w));
        }
        {
            const float4* s1 = reinterpret_cast<const float4*>(k1w + (size_t)(p * H_ + h) * EF_);
            float4 a = s1[0], b2 = s1[1];
            *reinterpret_cast<uint4*>(dst + 64) =
                make_uint4(pk(a.x, a.y), pk(a.z, a.w), pk(b2.x, b2.y), pk(b2.z, b2.w));
        }
        {
            const float4* s2 = reinterpret_cast<const float4*>(k2w + (size_t)(p * H_ + h) * T_);
#pragma unroll
            for (int q = 0; q < 4; q += 2) {
                float4 a = s2[q], b2 = s2[q + 1];
                *reinterpret_cast<uint4*>(dst + 72 + q * 4) =
                    make_uint4(pk(a.x, a.y), pk(a.z, a.w), pk(b2.x, b2.y), pk(b2.z, b2.w));
            }
        }
        *reinterpret_cast<uint4*>(dst + 88) = make_uint4((u32)f2bf(k1b[p * H_ + h]), 0, 0, 0);
        *reinterpret_cast<uint4*>(dst + 96) = make_uint4(0, 0, 0, 0);
        *reinterpret_cast<uint4*>(dst + 104) = make_uint4(0, 0, 0, 0);
        *reinterpret_cast<uint4*>(dst + 112) = make_uint4(0, 0, 0, 0);
        *reinterpret_cast<uint4*>(dst + 120) = make_uint4(0, 0, 0, 0);
    } else if (blk < 100) {  // efb[p][e][8] from ef[p][e][9] cols 0..8
        int flat = (blk - 68) * 256 + t;  // p*1024+e
        const float* s = ef + (size_t)flat * (EF_ + 1);
        float v0 = s[0], v1 = s[1], v2 = s[2], v3 = s[3], v4 = s[4], v5 = s[5], v6 = s[6], v7 = s[7];
        *reinterpret_cast<uint4*>(efb + (size_t)flat * 8) =
            make_uint4(pk(v0, v1), pk(v2, v3), pk(v4, v5), pk(v6, v7));
    } else {  // k5wb[p][16][128], pre-swizzled, rows 8..15 zero
        int p = blk - 100;
        int row = t >> 4, col8 = (t & 15) * 8;
        uint4 o = make_uint4(0, 0, 0, 0);
        if (row < 8) {
            const float4* s = reinterpret_cast<const float4*>(k5w + (size_t)(p * W_ + row) * H_ + col8);
            float4 a = s[0], b2 = s[1];
            o = make_uint4(pk(a.x, a.y), pk(a.z, a.w), pk(b2.x, b2.y), pk(b2.z, b2.w));
        }
        int ch = (col8 >> 3) ^ (row & 7);
        *reinterpret_cast<uint4*>(k5wb + (size_t)p * 2048 + row * 128 + ch * 8) = o;
    }
}

// ---------------- K1 (MFMA): rx[b,p,e,f] = sum_m rinc[p,e,m] * x[b,nbr[p,m],f] ----------------
__global__ __launch_bounds__(256) void k_rx(const float* __restrict__ x,
                                            const u16* __restrict__ rincbf,
                                            const int* __restrict__ nbr,
                                            u16* __restrict__ rxbf) {
    const int et = blockIdx.x, p = blockIdx.y, b = blockIdx.z;
    const int t = threadIdx.x, lane = t & 63, wid = t >> 6;
    __shared__ __align__(16) u16 A_lds[128 * 64];
    __shared__ __align__(16) u16 BT_lds[64 * 64];
    f32x4 acc[2][4];
#pragma unroll
    for (int i = 0; i < 2; i++)
#pragma unroll
        for (int j = 0; j < 4; j++) acc[i][j] = 0.f;

    const int e0 = et * 128;
    for (int c = 0; c < 4; c++) {
        const int m0 = c * 64;
        __syncthreads();
        {
            int ee = t >> 1, seg = t & 1;
            const uint4* src = reinterpret_cast<const uint4*>(
                rincbf + ((size_t)(p * e_ + e0 + ee) * m_ + m0 + seg * 32));
#pragma unroll
            for (int q = 0; q < 4; q++) {
                uint4 v = src[q];
                int ch = (seg * 4 + q) ^ (ee & 7);
                *reinterpret_cast<uint4*>(A_lds + ee * 64 + ch * 8) = v;
            }
        }
        {
            int mm = t >> 2, fq = (t & 3) * 16;
            int row = nbr[p * m_ + m0 + mm];
            const float4* sx = reinterpret_cast<const float4*>(
                x + (size_t)(b * N_ + row) * F_ + fq);
#pragma unroll
            for (int q = 0; q < 4; q++) {
                float4 v = sx[q];
                int f0 = fq + q * 4;
                BT_lds[swzi(f0 + 0, mm)] = f2bf(v.x);
                BT_lds[swzi(f0 + 1, mm)] = f2bf(v.y);
                BT_lds[swzi(f0 + 2, mm)] = f2bf(v.z);
                BT_lds[swzi(f0 + 3, mm)] = f2bf(v.w);
            }
        }
        __syncthreads();
        const int wm0 = wid * 32, r15 = lane & 15, g4 = lane >> 4;
#pragma unroll
        for (int ks = 0; ks < 2; ks++) {
            int kb = ks * 32 + g4 * 8;
            bf16x8 af[2], bfr[4];
#pragma unroll
            for (int mf = 0; mf < 2; mf++) af[mf] = ldfrag(A_lds, wm0 + mf * 16 + r15, kb);
#pragma unroll
            for (int nf = 0; nf < 4; nf++) bfr[nf] = ldfrag(BT_lds, nf * 16 + r15, kb);
#pragma unroll
            for (int mf = 0; mf < 2; mf++)
#pragma unroll
                for (int nf = 0; nf < 4; nf++)
                    acc[mf][nf] = __builtin_amdgcn_mfma_f32_16x16x32_bf16(af[mf], bfr[nf], acc[mf][nf], 0, 0, 0);
        }
    }
    const int r15 = lane & 15, g4 = lane >> 4;
#pragma unroll
    for (int mf = 0; mf < 2; mf++)
#pragma unroll
        for (int nf = 0; nf < 4; nf++)
#pragma unroll
            for (int r = 0; r < 4; r++) {
                int erow = e0 + wid * 32 + mf * 16 + g4 * 4 + r;
                int f = nf * 16 + r15;
                rxbf[((size_t)(b * P_ + p) * e_ + erow) * F_ + f] = f2bf(acc[mf][nf][r]);
            }
}

// ---------------- K2: uT[b,p,h,n] (bf16) = sum_f k3_w[p,h,f] * x[b,nodes[p,n],f] ----------------
__global__ __launch_bounds__(256) void k_u(const float* __restrict__ x,
                                           const float* __restrict__ k3w,
                                           const int* __restrict__ nodes,
                                           u16* __restrict__ uT) {
    const int p = blockIdx.x, b = blockIdx.y;
    const int t = threadIdx.x;
    const int th = t & 15;
    const int tn = t >> 4;
    __shared__ float xg[128 * 64];
    __shared__ float kw[128 * 64];
    for (int idx = t; idx < 8192; idx += 256) {
        int r = idx >> 6, f = idx & 63;
        int row = nodes[p * n_ + r];
        xg[swz64(r, f)] = x[(size_t)(b * N_ + row) * F_ + f];
        kw[swz64(r, f)] = k3w[(size_t)(p * H_ + r) * F_ + f];
    }
    __syncthreads();
    float acc[8][8];
#pragma unroll
    for (int i = 0; i < 8; i++)
#pragma unroll
        for (int j = 0; j < 8; j++) acc[i][j] = 0.f;
#pragma unroll 2
    for (int k4 = 0; k4 < 16; k4++) {
        float4 xv[8];
#pragma unroll
        for (int i = 0; i < 8; i++) xv[i] = ld64(xg, tn * 8 + i, k4);
#pragma unroll
        for (int j = 0; j < 8; j++) {
            float4 kv = ld64(kw, th * 8 + j, k4);
#pragma unroll
            for (int i = 0; i < 8; i++) {
                acc[i][j] += xv[i].x * kv.x + xv[i].y * kv.y + xv[i].z * kv.z + xv[i].w * kv.w;
            }
        }
    }
    // write transposed bf16: uT[h][n]
#pragma unroll
    for (int j = 0; j < 8; j++) {
        uint4 o = make_uint4(pk(acc[0][j], acc[1][j]), pk(acc[2][j], acc[3][j]),
                             pk(acc[4][j], acc[5][j]), pk(acc[6][j], acc[7][j]));
        *reinterpret_cast<uint4*>(uT + ((size_t)(b * P_ + p) * H_ + th * 8 + j) * n_ + tn * 8) = o;
    }
}

// ---------------- K3 (MFMA): kernel[b,p,e,w] ----------------
__global__ __launch_bounds__(256) void k_kern(const u16* __restrict__ lincT,
                                              const u16* __restrict__ uT,
                                              const u16* __restrict__ rxbf,
                                              const u16* __restrict__ Bw,
                                              const u16* __restrict__ efb,
                                              const float* __restrict__ tin,
                                              const u16* __restrict__ k5wb,
                                              const float* __restrict__ k5b,
                                              float* __restrict__ kern) {
    const int et = blockIdx.x, p = blockIdx.y, b = blockIdx.z;
    const int t = threadIdx.x, lane = t & 63, wid = t >> 6;
    const int r15 = lane & 15, g4 = lane >> 4;
    const int wm = (wid >> 1) * 64, wn = (wid & 1) * 64;
    __shared__ __align__(16) u16 S[128 * 128 + 16 * 128];
    u16* A_lds = S;
    u16* B_lds = S + 8192;
    u16* k5l = S + 16384;

    {
        uint4 v = reinterpret_cast<const uint4*>(k5wb + (size_t)p * 2048)[t];
        reinterpret_cast<uint4*>(k5l)[t] = v;
    }
    uint4 tinlo, tinhi;
    {
        const float4* s = reinterpret_cast<const float4*>(tin + b * T_);
        float4 a = s[0], b2 = s[1], c2 = s[2], d2 = s[3];
        tinlo = make_uint4(pk(a.x, a.y), pk(a.z, a.w), pk(b2.x, b2.y), pk(b2.z, b2.w));
        tinhi = make_uint4(pk(c2.x, c2.y), pk(c2.z, c2.w), pk(d2.x, d2.y), pk(d2.z, d2.w));
    }

    f32x4 acc[4][4];
#pragma unroll
    for (int i = 0; i < 4; i++)
#pragma unroll
        for (int j = 0; j < 4; j++) acc[i][j] = 0.f;

    const int e0 = et * 128;
    const size_t pb_e = (size_t)(b * P_ + p) * e_;
    const int row = t >> 1, half = t & 1;

    for (int c = 0; c < 4; c++) {
        __syncthreads();
        if (c < 2) {
            const uint4* src = reinterpret_cast<const uint4*>(
                lincT + ((size_t)(p * e_) + e0 + row) * n_ + c * 64 + half * 32);
#pragma unroll
            for (int q = 0; q < 4; q++) {
                uint4 v = src[q];
                int ch = (half * 4 + q) ^ (row & 7);
                *reinterpret_cast<uint4*>(A_lds + row * 64 + ch * 8) = v;
            }
        } else if (c == 2) {
            const uint4* src = reinterpret_cast<const uint4*>(
                rxbf + (pb_e + e0 + row) * F_ + half * 32);
#pragma unroll
            for (int q = 0; q < 4; q++) {
                uint4 v = src[q];
                int ch = (half * 4 + q) ^ (row & 7);
                *reinterpret_cast<uint4*>(A_lds + row * 64 + ch * 8) = v;
            }
        } else {
            uint4 w[4];
            if (half == 0) {
                w[0] = *reinterpret_cast<const uint4*>(efb + ((size_t)(p * e_) + e0 + row) * 8);
                w[1] = tinlo;
                w[2] = tinhi;
                w[3] = make_uint4(0x00003F80u, 0, 0, 0);
            } else {
                w[0] = w[1] = w[2] = w[3] = make_uint4(0, 0, 0, 0);
            }
#pragma unroll
            for (int q = 0; q < 4; q++) {
                int ch = (half * 4 + q) ^ (row & 7);
                *reinterpret_cast<uint4*>(A_lds + row * 64 + ch * 8) = w[q];
            }
        }
        {
            const uint4* src;
            if (c < 2)
                src = reinterpret_cast<const uint4*>(
                    uT + ((size_t)(b * P_ + p) * H_ + row) * n_ + c * 64 + half * 32);
            else
                src = reinterpret_cast<const uint4*>(
                    Bw + (size_t)(p * H_ + row) * 128 + (c - 2) * 64 + half * 32);
#pragma unroll
            for (int q = 0; q < 4; q++) {
                uint4 v = src[q];
                int ch = (half * 4 + q) ^ (row & 7);
                *reinterpret_cast<uint4*>(B_lds + row * 64 + ch * 8) = v;
            }
        }
        __syncthreads();
#pragma unroll
        for (int ks = 0; ks < 2; ks++) {
            int kb = ks * 32 + g4 * 8;
            bf16x8 af[4], bfr[4];
#pragma unroll
            for (int mf = 0; mf < 4; mf++) af[mf] = ldfrag(A_lds, wm + mf * 16 + r15, kb);
#pragma unroll
            for (int nf = 0; nf < 4; nf++) bfr[nf] = ldfrag(B_lds, wn + nf * 16 + r15, kb);
#pragma unroll
            for (int mf = 0; mf < 4; mf++)
#pragma unroll
                for (int nf = 0; nf < 4; nf++)
                    acc[mf][nf] = __builtin_amdgcn_mfma_f32_16x16x32_bf16(af[mf], bfr[nf], acc[mf][nf], 0, 0, 0);
        }
    }
    __syncthreads();
    u16* Kl = S;
#pragma unroll
    for (int mf = 0; mf < 4; mf++)
#pragma unroll
        for (int nf = 0; nf < 4; nf++)
#pragma unroll
            for (int r = 0; r < 4; r++) {
                int er = wm + mf * 16 + g4 * 4 + r;
                int hc = wn + nf * 16 + r15;
                Kl[swzi128(er, hc)] = f2bf(leakyf(acc[mf][nf][r], 0.02f));
            }
    __syncthreads();
    f32x4 acc2[2];
    acc2[0] = 0.f;
    acc2[1] = 0.f;
#pragma unroll
    for (int ks = 0; ks < 4; ks++) {
        int kb = ks * 32 + g4 * 8;
        bf16x8 bf5 = ldfrag128(k5l, r15, kb);
#pragma unroll
        for (int mf2 = 0; mf2 < 2; mf2++) {
            bf16x8 af = ldfrag128(Kl, wid * 32 + mf2 * 16 + r15, kb);
            acc2[mf2] = __builtin_amdgcn_mfma_f32_16x16x32_bf16(af, bf5, acc2[mf2], 0, 0, 0);
        }
    }
    if (r15 < 8) {
        float kb5 = k5b[p * W_ + r15];
#pragma unroll
        for (int mf2 = 0; mf2 < 2; mf2++)
#pragma unroll
            for (int r = 0; r < 4; r++) {
                int er = e0 + wid * 32 + mf2 * 16 + g4 * 4 + r;
                kern[(pb_e + er) * W_ + r15] = fmaxf(acc2[mf2][r] + kb5, 0.f);
            }
    }
}

// ---------------- K4 (MFMA): Q[b,p,e,g] = sum_{w,f} (kern[e,w]*rx[e,f]) * gcw[g,w*F+f] ----------------
__global__ __launch_bounds__(256) void k_q(const u16* __restrict__ rxbf,
                                           const float* __restrict__ kernb,
                                           const u16* __restrict__ gcwbf,
                                           u16* __restrict__ Qbf) {
    const int et = blockIdx.x, p = blockIdx.y, b = blockIdx.z;
    const int t = threadIdx.x, lane = t & 63, wid = t >> 6;
    __shared__ __align__(16) u16 A_lds[128 * 64];
    __shared__ __align__(16) u16 BT_lds[128 * 64];
    f32x4 acc[4][4];
#pragma unroll
    for (int i = 0; i < 4; i++)
#pragma unroll
        for (int j = 0; j < 4; j++) acc[i][j] = 0.f;

    const int e0 = et * 128;
    const size_t pb_e = (size_t)(b * P_ + p) * e_;
    const int wm = (wid >> 1) * 64, wn = (wid & 1) * 64;
    const int r15 = lane & 15, g4 = lane >> 4;

    for (int w = 0; w < 8; w++) {
        __syncthreads();
        {
            int ee = t >> 1, seg = t & 1;
            float ksc = kernb[(pb_e + e0 + ee) * W_ + w];
            const uint4* src = reinterpret_cast<const uint4*>(rxbf + (pb_e + e0 + ee) * F_ + seg * 32);
#pragma unroll
            for (int q = 0; q < 4; q++) {
                uint4 v = src[q];
                u32 vv[4] = {v.x, v.y, v.z, v.w};
                u32 ov[4];
#pragma unroll
                for (int q2 = 0; q2 < 4; q2++) {
                    float f0 = bf2f((u16)(vv[q2] & 0xFFFF)) * ksc;
                    float f1 = bf2f((u16)(vv[q2] >> 16)) * ksc;
                    ov[q2] = (u32)f2bf(f0) | ((u32)f2bf(f1) << 16);
                }
                int ch = (seg * 4 + q) ^ (ee & 7);
                *reinterpret_cast<uint4*>(A_lds + ee * 64 + ch * 8) =
                    make_uint4(ov[0], ov[1], ov[2], ov[3]);
            }
        }
        {
            int gg = t >> 1, seg = t & 1;
            const uint4* src = reinterpret_cast<const uint4*>(
                gcwbf + (size_t)(p * G_ + gg) * 512 + w * 64 + seg * 32);
#pragma unroll
            for (int q = 0; q < 4; q++) {
                uint4 v = src[q];
                int ch = (seg * 4 + q) ^ (gg & 7);
                *reinterpret_cast<uint4*>(BT_lds + gg * 64 + ch * 8) = v;
            }
        }
        __syncthreads();
#pragma unroll
        for (int ks = 0; ks < 2; ks++) {
            int kb = ks * 32 + g4 * 8;
            bf16x8 af[4], bfr[4];
#pragma unroll
            for (int mf = 0; mf < 4; mf++) af[mf] = ldfrag(A_lds, wm + mf * 16 + r15, kb);
#pragma unroll
            for (int nf = 0; nf < 4; nf++) bfr[nf] = ldfrag(BT_lds, wn + nf * 16 + r15, kb);
#pragma unroll
            for (int mf = 0; mf < 4; mf++)
#pragma unroll
                for (int nf = 0; nf < 4; nf++)
                    acc[mf][nf] = __builtin_amdgcn_mfma_f32_16x16x32_bf16(af[mf], bfr[nf], acc[mf][nf], 0, 0, 0);
        }
    }
#pragma unroll
    for (int mf = 0; mf < 4; mf++)
#pragma unroll
        for (int nf = 0; nf < 4; nf++)
#pragma unroll
            for (int r = 0; r < 4; r++) {
                int erow = e0 + wm + mf * 16 + g4 * 4 + r;
                int g = wn + nf * 16 + r15;
                Qbf[(pb_e + erow) * G_ + g] = f2bf(acc[mf][nf][r]);
            }
}

// ---------------- K5 (MFMA): y2[b,p,n,g] = relu(sum_e linc[n,e]*Q[e,g] + gcb[g]) ----------------
__global__ __launch_bounds__(256) void k_y2(const u16* __restrict__ lincbf,
                                            const u16* __restrict__ Qbf,
                                            const float* __restrict__ gcb,
                                            float* __restrict__ y2) {
    const int p = blockIdx.x, b = blockIdx.y;
    const int t = threadIdx.x, lane = t & 63, wid = t >> 6;
    __shared__ __align__(16) u16 A_lds[128 * 64];
    __shared__ __align__(16) u16 BT_lds[128 * 64];
    f32x4 acc[4][4];
#pragma unroll
    for (int i = 0; i < 4; i++)
#pragma unroll
        for (int j = 0; j < 4; j++) acc[i][j] = 0.f;

    const size_t pb_e = (size_t)(b * P_ + p) * e_;
    const int wm = (wid >> 1) * 64, wn = (wid & 1) * 64;
    const int r15 = lane & 15, g4 = lane >> 4;

    for (int c = 0; c < 16; c++) {
        const int e0 = c * 64;
        __syncthreads();
        {
            int nn = t >> 1, seg = t & 1;
            const uint4* src = reinterpret_cast<const uint4*>(
                lincbf + (size_t)(p * n_ + nn) * e_ + e0 + seg * 32);
#pragma unroll
            for (int q = 0; q < 4; q++) {
                uint4 v = src[q];
                int ch = (seg * 4 + q) ^ (nn & 7);
                *reinterpret_cast<uint4*>(A_lds + nn * 64 + ch * 8) = v;
            }
        }
        {
            int ek = t >> 2, gq = (t & 3) * 32;
            const uint4* src = reinterpret_cast<const uint4*>(Qbf + (pb_e + e0 + ek) * G_ + gq);
#pragma unroll
            for (int q = 0; q < 4; q++) {
                uint4 v = src[q];
                u32 vv[4] = {v.x, v.y, v.z, v.w};
#pragma unroll
                for (int q2 = 0; q2 < 4; q2++) {
                    int g0 = gq + q * 8 + q2 * 2;
                    BT_lds[swzi(g0, ek)] = (u16)(vv[q2] & 0xFFFF);
                    BT_lds[swzi(g0 + 1, ek)] = (u16)(vv[q2] >> 16);
                }
            }
        }
        __syncthreads();
#pragma unroll
        for (int ks = 0; ks < 2; ks++) {
            int kb = ks * 32 + g4 * 8;
            bf16x8 af[4], bfr[4];
#pragma unroll
            for (int mf = 0; mf < 4; mf++) af[mf] = ldfrag(A_lds, wm + mf * 16 + r15, kb);
#pragma unroll
            for (int nf = 0; nf < 4; nf++) bfr[nf] = ldfrag(BT_lds, wn + nf * 16 + r15, kb);
#pragma unroll
            for (int mf = 0; mf < 4; mf++)
#pragma unroll
                for (int nf = 0; nf < 4; nf++)
                    acc[mf][nf] = __builtin_amdgcn_mfma_f32_16x16x32_bf16(af[mf], bfr[nf], acc[mf][nf], 0, 0, 0);
        }
    }
#pragma unroll
    for (int mf = 0; mf < 4; mf++)
#pragma unroll
        for (int nf = 0; nf < 4; nf++) {
            int g = wn + nf * 16 + r15;
            float gb = gcb[p * G_ + g];
#pragma unroll
            for (int r = 0; r < 4; r++) {
                int nrow = wm + mf * 16 + g4 * 4 + r;
                y2[((size_t)(b * P_ + p) * n_ + nrow) * G_ + g] = fmaxf(acc[mf][nf][r] + gb, 0.f);
            }
        }
}

// ---------------- K6: hpart[ks,p,b,r] = sum_{k in slice} r0_w[p,r,k]*y2flat[b,p,k] ----------------
// 128 slices of 128 k. Thread tile 4r x 8b. y2 staged transposed [k][b] in LDS.
__global__ __launch_bounds__(256) void k_h1(const float* __restrict__ r0w,
                                            const float* __restrict__ y2,
                                            float* __restrict__ hpart) {
    const int ks = blockIdx.x;  // 0..127
    const int p = blockIdx.y;
    const int t = threadIdx.x;
    const int bg = t & 3;    // 4 groups x 8 b
    const int rg = t >> 2;   // 64 groups x 4 r
    __shared__ float yl[128 * 36];  // [k][b], pad 36
    const int kc = ks * 128;
    for (int idx = t; idx < 4096; idx += 256) {
        int bb = idx >> 7, kk = idx & 127;
        yl[kk * 36 + bb] = y2[(size_t)(bb * P_ + p) * (n_ * G_) + kc + kk];
    }
    __syncthreads();
    float acc[4][8];
#pragma unroll
    for (int i = 0; i < 4; i++)
#pragma unroll
        for (int j = 0; j < 8; j++) acc[i][j] = 0.f;

    const float* r0p = r0w + ((size_t)(p * R_) + rg * 4) * 16384 + kc;
#pragma unroll 2
    for (int kq = 0; kq < 32; kq++) {
        float4 r0v[4];
#pragma unroll
        for (int i = 0; i < 4; i++)
            r0v[i] = *reinterpret_cast<const float4*>(r0p + (size_t)i * 16384 + kq * 4);
#pragma unroll
        for (int qq = 0; qq < 4; qq++) {
            int k = kq * 4 + qq;
            float4 y0 = *reinterpret_cast<const float4*>(yl + k * 36 + bg * 8);
            float4 y1 = *reinterpret_cast<const float4*>(yl + k * 36 + bg * 8 + 4);
#pragma unroll
            for (int i = 0; i < 4; i++) {
                float a = reinterpret_cast<const float*>(&r0v[i])[qq];
                acc[i][0] += a * y0.x;
                acc[i][1] += a * y0.y;
                acc[i][2] += a * y0.z;
                acc[i][3] += a * y0.w;
                acc[i][4] += a * y1.x;
                acc[i][5] += a * y1.y;
                acc[i][6] += a * y1.z;
                acc[i][7] += a * y1.w;
            }
        }
    }
    // write hpart[ks][p][b][r] (r-contiguous for coalesced reduction in k_wres)
#pragma unroll
    for (int j = 0; j < 8; j++) {
        int b = bg * 8 + j;
        float4 v = make_float4(acc[0][j], acc[1][j], acc[2][j], acc[3][j]);
        *reinterpret_cast<float4*>(hpart + (((size_t)(ks * P_ + p) * 32 + b) * 256 + rg * 4)) = v;
    }
}

// ---------------- K7: h -> leaky -> w -> res ----------------
__global__ __launch_bounds__(128) void k_wres(const float* __restrict__ hpart,
                                              const float* __restrict__ r1w,
                                              const float* __restrict__ r1b,
                                              const float* __restrict__ r2w,
                                              const float* __restrict__ cap,
                                              const float* __restrict__ tin,
                                              const float* __restrict__ r3w,
                                              const float* __restrict__ r3b,
                                              const float* __restrict__ y2,
                                              float* __restrict__ res) {
    const int p = blockIdx.x, b = blockIdx.y;
    const int t = threadIdx.x;
    __shared__ float lh[256];
    __shared__ float wl[128];
    for (int rr = t; rr < 256; rr += 128) {
        float s = 0.f;
        for (int ks = 0; ks < 128; ks++)
            s += hpart[(((size_t)(ks * P_ + p) * 32 + b) * 256) + rr];
        for (int tt = 0; tt < T_; tt++) s += r1w[(size_t)(p * R_ + rr) * T_ + tt] * tin[b * T_ + tt];
        s += r1b[p * R_ + rr];
        for (int nn = 0; nn < n_; nn++) s += r2w[(size_t)(p * R_ + rr) * n_ + nn] * cap[p * n_ + nn];
        lh[rr] = leakyf(s, 0.01f);
    }
    __syncthreads();
    {
        const int nn = t;
        float accw = r3b[p * n_ + nn];
        const float* r3p = r3w + (size_t)(p * n_ + nn) * R_;
        for (int r = 0; r < 256; r += 4) {
            float4 rv = *reinterpret_cast<const float4*>(r3p + r);
            accw += rv.x * lh[r] + rv.y * lh[r + 1] + rv.z * lh[r + 2] + rv.w * lh[r + 3];
        }
        wl[nn] = fmaxf(accw, 0.f);
    }
    __syncthreads();
    {
        const int g = t;
        float a = 0.f;
        for (int nn = 0; nn < n_; nn++) a += wl[nn] * y2[((size_t)(b * P_ + p) * n_ + nn) * G_ + g];
        res[(b * P_ + p) * G_ + g] = a;
    }
}

// ---------------- K8: out[b,l] ----------------
__global__ __launch_bounds__(128) void k_out(const float* __restrict__ convw,
                                             const float* __restrict__ convb,
                                             const float* __restrict__ res,
                                             float* __restrict__ out) {
    const int b = blockIdx.x;
    const int t = threadIdx.x;
    __shared__ float rl[1024];
    for (int idx = t; idx < 1024; idx += 128) rl[idx] = res[b * 1024 + idx];
    __syncthreads();
    float a = convb[t];
    const float* cw = convw + (size_t)t * 1024;
    for (int gp = 0; gp < 1024; gp += 4) {
        float4 v = *reinterpret_cast<const float4*>(cw + gp);
        a += v.x * rl[((gp + 0) & 7) * 128 + ((gp + 0) >> 3)];
        a += v.y * rl[((gp + 1) & 7) * 128 + ((gp + 1) >> 3)];
        a += v.z * rl[((gp + 2) & 7) * 128 + ((gp + 2) >> 3)];
        a += v.w * rl[((gp + 3) & 7) * 128 + ((gp + 3) >> 3)];
    }
    out[b * L2_ + t] = leakyf(a, 0.02f);
}

extern "C" void kernel_launch(void* const* d_in, const int* in_sizes, int n_in,
                              void* d_out, int out_size, void* d_ws, size_t ws_size,
                              hipStream_t stream) {
    const float* x    = (const float*)d_in[0];
    const float* tin  = (const float*)d_in[1];
    const float* ef   = (const float*)d_in[2];
    const float* linc = (const float*)d_in[3];
    const float* rinc = (const float*)d_in[4];
    const float* cap  = (const float*)d_in[5];
    const float* k1w  = (const float*)d_in[6];
    const float* k1b  = (const float*)d_in[7];
    const float* k2w  = (const float*)d_in[8];
    const float* k3w  = (const float*)d_in[9];
    const float* k4w  = (const float*)d_in[10];
    const float* k5w  = (const float*)d_in[11];
    const float* k5b  = (const float*)d_in[12];
    const float* gcw  = (const float*)d_in[13];
    const float* gcb  = (const float*)d_in[14];
    const float* r0w  = (const float*)d_in[15];
    const float* r1w  = (const float*)d_in[16];
    const float* r1b  = (const float*)d_in[17];
    const float* r2w  = (const float*)d_in[18];
    const float* r3w  = (const float*)d_in[19];
    const float* r3b  = (const float*)d_in[20];
    const float* convw = (const float*)d_in[21];
    const float* convb = (const float*)d_in[22];
    const int* nodes  = (const int*)d_in[23];
    const int* nbr    = (const int*)d_in[24];
    float* out = (float*)d_out;

    float* ws = (float*)d_ws;
    u16*   rxbf   = (u16*)ws;                  // [0, 8388608) f-slots
    u16*   uTbf   = (u16*)(ws + 8388608);      // [8388608, 10485760)
    float* kernb  = ws + 10485760;             // [10485760, 12582912)
    u16*   Qbf    = (u16*)(ws + 12582912);     // [12582912, 29360128)
    float* y2b    = ws + 29360128;             // [29360128, 33554432)
    u16*   lincbf = (u16*)(ws + 33554432);     // 524288 slots
    u16*   lincT  = (u16*)(ws + 34078720);     // 524288
    u16*   rincbf = (u16*)(ws + 34603008);     // 1048576
    u16*   gcwbf  = (u16*)(ws + 35651584);     // 262144
    u16*   Bwbf   = (u16*)(ws + 35913728);     // 65536
    u16*   efbf   = (u16*)(ws + 35979264);     // 32768
    u16*   k5wbf  = (u16*)(ws + 36012032);     // 8192
    float* hpart  = ws;                        // 8,388,608 floats: aliases rx region (dead after k_q)
    float* resb   = ws + 10485760;             // aliases kernb (dead after k_q)

    k_prep <<<3584, 256, 0, stream>>>(linc, rinc, gcw, lincbf, rincbf, gcwbf);
    k_prep2<<<108, 256, 0, stream>>>(linc, k4w, k1w, k2w, k1b, ef, k5w, lincT, Bwbf, efbf, k5wbf);
    k_rx  <<<dim3(8, P_, B_), 256, 0, stream>>>(x, rincbf, nbr, rxbf);
    k_u   <<<dim3(P_, B_),    256, 0, stream>>>(x, k3w, nodes, uTbf);
    k_kern<<<dim3(8, P_, B_), 256, 0, stream>>>(lincT, uTbf, rxbf, Bwbf, efbf, tin, k5wbf, k5b, kernb);
    k_q   <<<dim3(8, P_, B_), 256, 0, stream>>>(rxbf, kernb, gcwbf, Qbf);
    k_y2  <<<dim3(P_, B_),    256, 0, stream>>>(lincbf, Qbf, gcb, y2b);
    k_h1  <<<dim3(128, P_),   256, 0, stream>>>(r0w, y2b, hpart);
    k_wres<<<dim3(P_, B_),    128, 0, stream>>>(hpart, r1w, r1b, r2w, cap, tin, r3w, r3b, y2b, resb);
    k_out <<<B_, 128, 0, stream>>>(convw, convb, resb, out);
}

// Round 5
// 296.342 us; speedup vs baseline: 4.9067x; 1.1109x over previous
//
#include <hip/hip_runtime.h>
#include <math.h>

#define B_ 32
#define N_ 1024
#define F_ 64
#define P_ 8
#define n_ 128
#define m_ 256
#define e_ 1024
#define EF_ 8
#define T_ 16
#define H_ 128
#define W_ 8
#define G_ 128
#define R_ 256
#define L2_ 128

typedef unsigned short u16;
typedef unsigned int u32;
typedef __attribute__((ext_vector_type(8))) short bf16x8;
typedef __attribute__((ext_vector_type(4))) float f32x4;

__device__ __forceinline__ float leakyf(float z, float s) { return z >= 0.f ? z : s * z; }

__device__ __forceinline__ u16 f2bf(float f) {
    u32 u = __float_as_uint(f);
    u += 0x7FFFu + ((u >> 16) & 1u);
    return (u16)(u >> 16);
}
__device__ __forceinline__ float bf2f(u16 h) { return __uint_as_float(((u32)h) << 16); }
__device__ __forceinline__ u32 pk(float a, float b) { return (u32)f2bf(a) | ((u32)f2bf(b) << 16); }

// ---- f32 LDS helpers ----
__device__ __forceinline__ int swz64(int r, int c) {
    return r * 64 + ((((c >> 2) ^ ((r >> 3) & 15)) << 2) | (c & 3));
}
__device__ __forceinline__ float4 ld64(const float* lds, int r, int c4) {
    return *reinterpret_cast<const float4*>(lds + r * 64 + ((c4 ^ ((r >> 3) & 15)) << 2));
}

// ---- bf16 LDS tiles: [rows][64] and [rows][128], chunk-of-8 XOR swizzle ----
__device__ __forceinline__ int swzi(int row, int col) {
    return row * 64 + ((((col >> 3) ^ (row & 7)) << 3) | (col & 7));
}
__device__ __forceinline__ bf16x8 ldfrag(const u16* lds, int row, int kb) {
    return *reinterpret_cast<const bf16x8*>(lds + row * 64 + ((((kb >> 3) ^ (row & 7)) << 3)));
}
__device__ __forceinline__ int swzi128(int row, int col) {
    return row * 128 + ((((col >> 3) ^ (row & 7)) << 3) | (col & 7));
}
__device__ __forceinline__ bf16x8 ldfrag128(const u16* lds, int row, int kb) {
    return *reinterpret_cast<const bf16x8*>(lds + row * 128 + ((((kb >> 3) ^ (row & 7)) << 3)));
}

// ---------------- prep: f32 -> bf16 copies of linc, rinc, gcw ----------------
__global__ __launch_bounds__(256) void k_prep(const float* __restrict__ linc,
                                              const float* __restrict__ rinc,
                                              const float* __restrict__ gcw,
                                              u16* __restrict__ lincbf,
                                              u16* __restrict__ rincbf,
                                              u16* __restrict__ gcwbf) {
    int i = blockIdx.x * 256 + threadIdx.x;
    const float* src;
    u16* dst;
    int base;
    if (i < 262144) { src = linc; dst = lincbf; base = 0; }
    else if (i < 786432) { src = rinc; dst = rincbf; base = 262144; }
    else { src = gcw; dst = gcwbf; base = 786432; }
    int j = i - base;
    float4 v = reinterpret_cast<const float4*>(src)[j];
    ushort4 o = make_ushort4(f2bf(v.x), f2bf(v.y), f2bf(v.z), f2bf(v.w));
    reinterpret_cast<ushort4*>(dst)[j] = o;
}

// ---------------- prep2: lincT, Bw(k4w|k1w|k2w|k1b|0), efbf, k5w tile ----------------
__global__ __launch_bounds__(256) void k_prep2(const float* __restrict__ linc,
                                               const float* __restrict__ k4w,
                                               const float* __restrict__ k1w,
                                               const float* __restrict__ k2w,
                                               const float* __restrict__ k1b,
                                               const float* __restrict__ ef,
                                               const float* __restrict__ k5w,
                                               u16* __restrict__ lincT,
                                               u16* __restrict__ Bw,
                                               u16* __restrict__ efb,
                                               u16* __restrict__ k5wb) {
    const int blk = blockIdx.x, t = threadIdx.x;
    if (blk < 64) {  // transpose linc[p][n][e] tile -> lincT[p][e][n]
        const int p = blk >> 3, et = blk & 7, e0 = et * 128;
        __shared__ u16 S[128 * 128];
        {
            const int nn = t >> 1, seg = (t & 1) * 64;
            const float4* src = reinterpret_cast<const float4*>(
                linc + (size_t)(p * n_ + nn) * e_ + e0 + seg);
#pragma unroll
            for (int q = 0; q < 16; q += 2) {
                float4 a = src[q], b2 = src[q + 1];
                uint4 o = make_uint4(pk(a.x, a.y), pk(a.z, a.w), pk(b2.x, b2.y), pk(b2.z, b2.w));
                int colbase = seg + q * 4;
                int ch = (colbase >> 3) ^ (nn & 7);
                *reinterpret_cast<uint4*>(S + nn * 128 + ch * 8) = o;
            }
        }
        __syncthreads();
        {
            const int e = t >> 1, ns = (t & 1) * 64;
            u16* dst = lincT + ((size_t)(p * e_) + e0 + e) * n_ + ns;
#pragma unroll
            for (int q = 0; q < 8; q++) {
                u16 v[8];
#pragma unroll
                for (int k = 0; k < 8; k++) v[k] = S[swzi128(ns + q * 8 + k, e)];
                uint4 o = make_uint4((u32)v[0] | ((u32)v[1] << 16), (u32)v[2] | ((u32)v[3] << 16),
                                     (u32)v[4] | ((u32)v[5] << 16), (u32)v[6] | ((u32)v[7] << 16));
                *reinterpret_cast<uint4*>(dst + q * 8) = o;
            }
        }
    } else if (blk < 68) {  // Bw[p][h][128] = k4w(64) | k1w(8) | k2w(16) | k1b(1) | 0(39)
        int flat = (blk - 64) * 256 + t;  // p*128+h
        int p = flat >> 7, h = flat & 127;
        u16* dst = Bw + (size_t)flat * 128;
        const float4* s4 = reinterpret_cast<const float4*>(k4w + (size_t)(p * H_ + h) * F_);
#pragma unroll
        for (int q = 0; q < 16; q += 2) {
            float4 a = s4[q], b2 = s4[q + 1];
            *reinterpret_cast<uint4*>(dst + q * 4) =
                make_uint4(pk(a.x, a.y), pk(a.z, a.w), pk(b2.x, b2.y), pk(b2.z, b2.w));
        }
        {
            const float4* s1 = reinterpret_cast<const float4*>(k1w + (size_t)(p * H_ + h) * EF_);
            float4 a = s1[0], b2 = s1[1];
            *reinterpret_cast<uint4*>(dst + 64) =
                make_uint4(pk(a.x, a.y), pk(a.z, a.w), pk(b2.x, b2.y), pk(b2.z, b2.w));
        }
        {
            const float4* s2 = reinterpret_cast<const float4*>(k2w + (size_t)(p * H_ + h) * T_);
#pragma unroll
            for (int q = 0; q < 4; q += 2) {
                float4 a = s2[q], b2 = s2[q + 1];
                *reinterpret_cast<uint4*>(dst + 72 + q * 4) =
                    make_uint4(pk(a.x, a.y), pk(a.z, a.w), pk(b2.x, b2.y), pk(b2.z, b2.w));
            }
        }
        *reinterpret_cast<uint4*>(dst + 88) = make_uint4((u32)f2bf(k1b[p * H_ + h]), 0, 0, 0);
        *reinterpret_cast<uint4*>(dst + 96) = make_uint4(0, 0, 0, 0);
        *reinterpret_cast<uint4*>(dst + 104) = make_uint4(0, 0, 0, 0);
        *reinterpret_cast<uint4*>(dst + 112) = make_uint4(0, 0, 0, 0);
        *reinterpret_cast<uint4*>(dst + 120) = make_uint4(0, 0, 0, 0);
    } else if (blk < 100) {  // efb[p][e][8] from ef[p][e][9] cols 0..8
        int flat = (blk - 68) * 256 + t;  // p*1024+e
        const float* s = ef + (size_t)flat * (EF_ + 1);
        float v0 = s[0], v1 = s[1], v2 = s[2], v3 = s[3], v4 = s[4], v5 = s[5], v6 = s[6], v7 = s[7];
        *reinterpret_cast<uint4*>(efb + (size_t)flat * 8) =
            make_uint4(pk(v0, v1), pk(v2, v3), pk(v4, v5), pk(v6, v7));
    } else {  // k5wb[p][16][128], pre-swizzled, rows 8..15 zero
        int p = blk - 100;
        int row = t >> 4, col8 = (t & 15) * 8;
        uint4 o = make_uint4(0, 0, 0, 0);
        if (row < 8) {
            const float4* s = reinterpret_cast<const float4*>(k5w + (size_t)(p * W_ + row) * H_ + col8);
            float4 a = s[0], b2 = s[1];
            o = make_uint4(pk(a.x, a.y), pk(a.z, a.w), pk(b2.x, b2.y), pk(b2.z, b2.w));
        }
        int ch = (col8 >> 3) ^ (row & 7);
        *reinterpret_cast<uint4*>(k5wb + (size_t)p * 2048 + row * 128 + ch * 8) = o;
    }
}

// ---------------- K1 (MFMA): rx[b,p,e,f] = sum_m rinc[p,e,m] * x[b,nbr[p,m],f] ----------------
__global__ __launch_bounds__(256) void k_rx(const float* __restrict__ x,
                                            const u16* __restrict__ rincbf,
                                            const int* __restrict__ nbr,
                                            u16* __restrict__ rxbf) {
    const int et = blockIdx.x, p = blockIdx.y, b = blockIdx.z;
    const int t = threadIdx.x, lane = t & 63, wid = t >> 6;
    __shared__ __align__(16) u16 A_lds[128 * 64];
    __shared__ __align__(16) u16 BT_lds[64 * 64];
    f32x4 acc[2][4];
#pragma unroll
    for (int i = 0; i < 2; i++)
#pragma unroll
        for (int j = 0; j < 4; j++) acc[i][j] = 0.f;

    const int e0 = et * 128;
    for (int c = 0; c < 4; c++) {
        const int m0 = c * 64;
        __syncthreads();
        {
            int ee = t >> 1, seg = t & 1;
            const uint4* src = reinterpret_cast<const uint4*>(
                rincbf + ((size_t)(p * e_ + e0 + ee) * m_ + m0 + seg * 32));
#pragma unroll
            for (int q = 0; q < 4; q++) {
                uint4 v = src[q];
                int ch = (seg * 4 + q) ^ (ee & 7);
                *reinterpret_cast<uint4*>(A_lds + ee * 64 + ch * 8) = v;
            }
        }
        {
            int mm = t >> 2, fq = (t & 3) * 16;
            int row = nbr[p * m_ + m0 + mm];
            const float4* sx = reinterpret_cast<const float4*>(
                x + (size_t)(b * N_ + row) * F_ + fq);
#pragma unroll
            for (int q = 0; q < 4; q++) {
                float4 v = sx[q];
                int f0 = fq + q * 4;
                BT_lds[swzi(f0 + 0, mm)] = f2bf(v.x);
                BT_lds[swzi(f0 + 1, mm)] = f2bf(v.y);
                BT_lds[swzi(f0 + 2, mm)] = f2bf(v.z);
                BT_lds[swzi(f0 + 3, mm)] = f2bf(v.w);
            }
        }
        __syncthreads();
        const int wm0 = wid * 32, r15 = lane & 15, g4 = lane >> 4;
#pragma unroll
        for (int ks = 0; ks < 2; ks++) {
            int kb = ks * 32 + g4 * 8;
            bf16x8 af[2], bfr[4];
#pragma unroll
            for (int mf = 0; mf < 2; mf++) af[mf] = ldfrag(A_lds, wm0 + mf * 16 + r15, kb);
#pragma unroll
            for (int nf = 0; nf < 4; nf++) bfr[nf] = ldfrag(BT_lds, nf * 16 + r15, kb);
#pragma unroll
            for (int mf = 0; mf < 2; mf++)
#pragma unroll
                for (int nf = 0; nf < 4; nf++)
                    acc[mf][nf] = __builtin_amdgcn_mfma_f32_16x16x32_bf16(af[mf], bfr[nf], acc[mf][nf], 0, 0, 0);
        }
    }
    const int r15 = lane & 15, g4 = lane >> 4;
#pragma unroll
    for (int mf = 0; mf < 2; mf++)
#pragma unroll
        for (int nf = 0; nf < 4; nf++)
#pragma unroll
            for (int r = 0; r < 4; r++) {
                int erow = e0 + wid * 32 + mf * 16 + g4 * 4 + r;
                int f = nf * 16 + r15;
                rxbf[((size_t)(b * P_ + p) * e_ + erow) * F_ + f] = f2bf(acc[mf][nf][r]);
            }
}

// ---------------- K2: uT[b,p,h,n] (bf16) = sum_f k3_w[p,h,f] * x[b,nodes[p,n],f] ----------------
__global__ __launch_bounds__(256) void k_u(const float* __restrict__ x,
                                           const float* __restrict__ k3w,
                                           const int* __restrict__ nodes,
                                           u16* __restrict__ uT) {
    const int p = blockIdx.x, b = blockIdx.y;
    const int t = threadIdx.x;
    const int th = t & 15;
    const int tn = t >> 4;
    __shared__ float xg[128 * 64];
    __shared__ float kw[128 * 64];
    for (int idx = t; idx < 8192; idx += 256) {
        int r = idx >> 6, f = idx & 63;
        int row = nodes[p * n_ + r];
        xg[swz64(r, f)] = x[(size_t)(b * N_ + row) * F_ + f];
        kw[swz64(r, f)] = k3w[(size_t)(p * H_ + r) * F_ + f];
    }
    __syncthreads();
    float acc[8][8];
#pragma unroll
    for (int i = 0; i < 8; i++)
#pragma unroll
        for (int j = 0; j < 8; j++) acc[i][j] = 0.f;
#pragma unroll 2
    for (int k4 = 0; k4 < 16; k4++) {
        float4 xv[8];
#pragma unroll
        for (int i = 0; i < 8; i++) xv[i] = ld64(xg, tn * 8 + i, k4);
#pragma unroll
        for (int j = 0; j < 8; j++) {
            float4 kv = ld64(kw, th * 8 + j, k4);
#pragma unroll
            for (int i = 0; i < 8; i++) {
                acc[i][j] += xv[i].x * kv.x + xv[i].y * kv.y + xv[i].z * kv.z + xv[i].w * kv.w;
            }
        }
    }
    // write transposed bf16: uT[h][n]
#pragma unroll
    for (int j = 0; j < 8; j++) {
        uint4 o = make_uint4(pk(acc[0][j], acc[1][j]), pk(acc[2][j], acc[3][j]),
                             pk(acc[4][j], acc[5][j]), pk(acc[6][j], acc[7][j]));
        *reinterpret_cast<uint4*>(uT + ((size_t)(b * P_ + p) * H_ + th * 8 + j) * n_ + tn * 8) = o;
    }
}

// ---------------- K3 (MFMA): kernel[b,p,e,w] ----------------
__global__ __launch_bounds__(256) void k_kern(const u16* __restrict__ lincT,
                                              const u16* __restrict__ uT,
                                              const u16* __restrict__ rxbf,
                                              const u16* __restrict__ Bw,
                                              const u16* __restrict__ efb,
                                              const float* __restrict__ tin,
                                              const u16* __restrict__ k5wb,
                                              const float* __restrict__ k5b,
                                              float* __restrict__ kern) {
    const int et = blockIdx.x, p = blockIdx.y, b = blockIdx.z;
    const int t = threadIdx.x, lane = t & 63, wid = t >> 6;
    const int r15 = lane & 15, g4 = lane >> 4;
    const int wm = (wid >> 1) * 64, wn = (wid & 1) * 64;
    __shared__ __align__(16) u16 S[128 * 128 + 16 * 128];
    u16* A_lds = S;
    u16* B_lds = S + 8192;
    u16* k5l = S + 16384;

    {
        uint4 v = reinterpret_cast<const uint4*>(k5wb + (size_t)p * 2048)[t];
        reinterpret_cast<uint4*>(k5l)[t] = v;
    }
    uint4 tinlo, tinhi;
    {
        const float4* s = reinterpret_cast<const float4*>(tin + b * T_);
        float4 a = s[0], b2 = s[1], c2 = s[2], d2 = s[3];
        tinlo = make_uint4(pk(a.x, a.y), pk(a.z, a.w), pk(b2.x, b2.y), pk(b2.z, b2.w));
        tinhi = make_uint4(pk(c2.x, c2.y), pk(c2.z, c2.w), pk(d2.x, d2.y), pk(d2.z, d2.w));
    }

    f32x4 acc[4][4];
#pragma unroll
    for (int i = 0; i < 4; i++)
#pragma unroll
        for (int j = 0; j < 4; j++) acc[i][j] = 0.f;

    const int e0 = et * 128;
    const size_t pb_e = (size_t)(b * P_ + p) * e_;
    const int row = t >> 1, half = t & 1;

    for (int c = 0; c < 4; c++) {
        __syncthreads();
        if (c < 2) {
            const uint4* src = reinterpret_cast<const uint4*>(
                lincT + ((size_t)(p * e_) + e0 + row) * n_ + c * 64 + half * 32);
#pragma unroll
            for (int q = 0; q < 4; q++) {
                uint4 v = src[q];
                int ch = (half * 4 + q) ^ (row & 7);
                *reinterpret_cast<uint4*>(A_lds + row * 64 + ch * 8) = v;
            }
        } else if (c == 2) {
            const uint4* src = reinterpret_cast<const uint4*>(
                rxbf + (pb_e + e0 + row) * F_ + half * 32);
#pragma unroll
            for (int q = 0; q < 4; q++) {
                uint4 v = src[q];
                int ch = (half * 4 + q) ^ (row & 7);
                *reinterpret_cast<uint4*>(A_lds + row * 64 + ch * 8) = v;
            }
        } else {
            uint4 w[4];
            if (half == 0) {
                w[0] = *reinterpret_cast<const uint4*>(efb + ((size_t)(p * e_) + e0 + row) * 8);
                w[1] = tinlo;
                w[2] = tinhi;
                w[3] = make_uint4(0x00003F80u, 0, 0, 0);
            } else {
                w[0] = w[1] = w[2] = w[3] = make_uint4(0, 0, 0, 0);
            }
#pragma unroll
            for (int q = 0; q < 4; q++) {
                int ch = (half * 4 + q) ^ (row & 7);
                *reinterpret_cast<uint4*>(A_lds + row * 64 + ch * 8) = w[q];
            }
        }
        {
            const uint4* src;
            if (c < 2)
                src = reinterpret_cast<const uint4*>(
                    uT + ((size_t)(b * P_ + p) * H_ + row) * n_ + c * 64 + half * 32);
            else
                src = reinterpret_cast<const uint4*>(
                    Bw + (size_t)(p * H_ + row) * 128 + (c - 2) * 64 + half * 32);
#pragma unroll
            for (int q = 0; q < 4; q++) {
                uint4 v = src[q];
                int ch = (half * 4 + q) ^ (row & 7);
                *reinterpret_cast<uint4*>(B_lds + row * 64 + ch * 8) = v;
            }
        }
        __syncthreads();
#pragma unroll
        for (int ks = 0; ks < 2; ks++) {
            int kb = ks * 32 + g4 * 8;
            bf16x8 af[4], bfr[4];
#pragma unroll
            for (int mf = 0; mf < 4; mf++) af[mf] = ldfrag(A_lds, wm + mf * 16 + r15, kb);
#pragma unroll
            for (int nf = 0; nf < 4; nf++) bfr[nf] = ldfrag(B_lds, wn + nf * 16 + r15, kb);
#pragma unroll
            for (int mf = 0; mf < 4; mf++)
#pragma unroll
                for (int nf = 0; nf < 4; nf++)
                    acc[mf][nf] = __builtin_amdgcn_mfma_f32_16x16x32_bf16(af[mf], bfr[nf], acc[mf][nf], 0, 0, 0);
        }
    }
    __syncthreads();
    u16* Kl = S;
#pragma unroll
    for (int mf = 0; mf < 4; mf++)
#pragma unroll
        for (int nf = 0; nf < 4; nf++)
#pragma unroll
            for (int r = 0; r < 4; r++) {
                int er = wm + mf * 16 + g4 * 4 + r;
                int hc = wn + nf * 16 + r15;
                Kl[swzi128(er, hc)] = f2bf(leakyf(acc[mf][nf][r], 0.02f));
            }
    __syncthreads();
    f32x4 acc2[2];
    acc2[0] = 0.f;
    acc2[1] = 0.f;
#pragma unroll
    for (int ks = 0; ks < 4; ks++) {
        int kb = ks * 32 + g4 * 8;
        bf16x8 bf5 = ldfrag128(k5l, r15, kb);
#pragma unroll
        for (int mf2 = 0; mf2 < 2; mf2++) {
            bf16x8 af = ldfrag128(Kl, wid * 32 + mf2 * 16 + r15, kb);
            acc2[mf2] = __builtin_amdgcn_mfma_f32_16x16x32_bf16(af, bf5, acc2[mf2], 0, 0, 0);
        }
    }
    if (r15 < 8) {
        float kb5 = k5b[p * W_ + r15];
#pragma unroll
        for (int mf2 = 0; mf2 < 2; mf2++)
#pragma unroll
            for (int r = 0; r < 4; r++) {
                int er = e0 + wid * 32 + mf2 * 16 + g4 * 4 + r;
                kern[(pb_e + er) * W_ + r15] = fmaxf(acc2[mf2][r] + kb5, 0.f);
            }
    }
}

// ---------------- K4 (MFMA): Q[b,p,e,g] = sum_{w,f} (kern[e,w]*rx[e,f]) * gcw[g,w*F+f] ----------------
__global__ __launch_bounds__(256) void k_q(const u16* __restrict__ rxbf,
                                           const float* __restrict__ kernb,
                                           const u16* __restrict__ gcwbf,
                                           u16* __restrict__ Qbf) {
    const int et = blockIdx.x, p = blockIdx.y, b = blockIdx.z;
    const int t = threadIdx.x, lane = t & 63, wid = t >> 6;
    __shared__ __align__(16) u16 A_lds[128 * 64];
    __shared__ __align__(16) u16 BT_lds[128 * 64];
    f32x4 acc[4][4];
#pragma unroll
    for (int i = 0; i < 4; i++)
#pragma unroll
        for (int j = 0; j < 4; j++) acc[i][j] = 0.f;

    const int e0 = et * 128;
    const size_t pb_e = (size_t)(b * P_ + p) * e_;
    const int wm = (wid >> 1) * 64, wn = (wid & 1) * 64;
    const int r15 = lane & 15, g4 = lane >> 4;

    for (int w = 0; w < 8; w++) {
        __syncthreads();
        {
            int ee = t >> 1, seg = t & 1;
            float ksc = kernb[(pb_e + e0 + ee) * W_ + w];
            const uint4* src = reinterpret_cast<const uint4*>(rxbf + (pb_e + e0 + ee) * F_ + seg * 32);
#pragma unroll
            for (int q = 0; q < 4; q++) {
                uint4 v = src[q];
                u32 vv[4] = {v.x, v.y, v.z, v.w};
                u32 ov[4];
#pragma unroll
                for (int q2 = 0; q2 < 4; q2++) {
                    float f0 = bf2f((u16)(vv[q2] & 0xFFFF)) * ksc;
                    float f1 = bf2f((u16)(vv[q2] >> 16)) * ksc;
                    ov[q2] = (u32)f2bf(f0) | ((u32)f2bf(f1) << 16);
                }
                int ch = (seg * 4 + q) ^ (ee & 7);
                *reinterpret_cast<uint4*>(A_lds + ee * 64 + ch * 8) =
                    make_uint4(ov[0], ov[1], ov[2], ov[3]);
            }
        }
        {
            int gg = t >> 1, seg = t & 1;
            const uint4* src = reinterpret_cast<const uint4*>(
                gcwbf + (size_t)(p * G_ + gg) * 512 + w * 64 + seg * 32);
#pragma unroll
            for (int q = 0; q < 4; q++) {
                uint4 v = src[q];
                int ch = (seg * 4 + q) ^ (gg & 7);
                *reinterpret_cast<uint4*>(BT_lds + gg * 64 + ch * 8) = v;
            }
        }
        __syncthreads();
#pragma unroll
        for (int ks = 0; ks < 2; ks++) {
            int kb = ks * 32 + g4 * 8;
            bf16x8 af[4], bfr[4];
#pragma unroll
            for (int mf = 0; mf < 4; mf++) af[mf] = ldfrag(A_lds, wm + mf * 16 + r15, kb);
#pragma unroll
            for (int nf = 0; nf < 4; nf++) bfr[nf] = ldfrag(BT_lds, wn + nf * 16 + r15, kb);
#pragma unroll
            for (int mf = 0; mf < 4; mf++)
#pragma unroll
                for (int nf = 0; nf < 4; nf++)
                    acc[mf][nf] = __builtin_amdgcn_mfma_f32_16x16x32_bf16(af[mf], bfr[nf], acc[mf][nf], 0, 0, 0);
        }
    }
#pragma unroll
    for (int mf = 0; mf < 4; mf++)
#pragma unroll
        for (int nf = 0; nf < 4; nf++)
#pragma unroll
            for (int r = 0; r < 4; r++) {
                int erow = e0 + wm + mf * 16 + g4 * 4 + r;
                int g = wn + nf * 16 + r15;
                Qbf[(pb_e + erow) * G_ + g] = f2bf(acc[mf][nf][r]);
            }
}

// ---------------- K5 (MFMA): y2[b,p,n,g] = relu(sum_e linc[n,e]*Q[e,g] + gcb[g]) ----------------
__global__ __launch_bounds__(256) void k_y2(const u16* __restrict__ lincbf,
                                            const u16* __restrict__ Qbf,
                                            const float* __restrict__ gcb,
                                            float* __restrict__ y2) {
    const int p = blockIdx.x, b = blockIdx.y;
    const int t = threadIdx.x, lane = t & 63, wid = t >> 6;
    __shared__ __align__(16) u16 A_lds[128 * 64];
    __shared__ __align__(16) u16 BT_lds[128 * 64];
    f32x4 acc[4][4];
#pragma unroll
    for (int i = 0; i < 4; i++)
#pragma unroll
        for (int j = 0; j < 4; j++) acc[i][j] = 0.f;

    const size_t pb_e = (size_t)(b * P_ + p) * e_;
    const int wm = (wid >> 1) * 64, wn = (wid & 1) * 64;
    const int r15 = lane & 15, g4 = lane >> 4;

    for (int c = 0; c < 16; c++) {
        const int e0 = c * 64;
        __syncthreads();
        {
            int nn = t >> 1, seg = t & 1;
            const uint4* src = reinterpret_cast<const uint4*>(
                lincbf + (size_t)(p * n_ + nn) * e_ + e0 + seg * 32);
#pragma unroll
            for (int q = 0; q < 4; q++) {
                uint4 v = src[q];
                int ch = (seg * 4 + q) ^ (nn & 7);
                *reinterpret_cast<uint4*>(A_lds + nn * 64 + ch * 8) = v;
            }
        }
        {
            int ek = t >> 2, gq = (t & 3) * 32;
            const uint4* src = reinterpret_cast<const uint4*>(Qbf + (pb_e + e0 + ek) * G_ + gq);
#pragma unroll
            for (int q = 0; q < 4; q++) {
                uint4 v = src[q];
                u32 vv[4] = {v.x, v.y, v.z, v.w};
#pragma unroll
                for (int q2 = 0; q2 < 4; q2++) {
                    int g0 = gq + q * 8 + q2 * 2;
                    BT_lds[swzi(g0, ek)] = (u16)(vv[q2] & 0xFFFF);
                    BT_lds[swzi(g0 + 1, ek)] = (u16)(vv[q2] >> 16);
                }
            }
        }
        __syncthreads();
#pragma unroll
        for (int ks = 0; ks < 2; ks++) {
            int kb = ks * 32 + g4 * 8;
            bf16x8 af[4], bfr[4];
#pragma unroll
            for (int mf = 0; mf < 4; mf++) af[mf] = ldfrag(A_lds, wm + mf * 16 + r15, kb);
#pragma unroll
            for (int nf = 0; nf < 4; nf++) bfr[nf] = ldfrag(BT_lds, wn + nf * 16 + r15, kb);
#pragma unroll
            for (int mf = 0; mf < 4; mf++)
#pragma unroll
                for (int nf = 0; nf < 4; nf++)
                    acc[mf][nf] = __builtin_amdgcn_mfma_f32_16x16x32_bf16(af[mf], bfr[nf], acc[mf][nf], 0, 0, 0);
        }
    }
#pragma unroll
    for (int mf = 0; mf < 4; mf++)
#pragma unroll
        for (int nf = 0; nf < 4; nf++) {
            int g = wn + nf * 16 + r15;
            float gb = gcb[p * G_ + g];
#pragma unroll
            for (int r = 0; r < 4; r++) {
                int nrow = wm + mf * 16 + g4 * 4 + r;
                y2[((size_t)(b * P_ + p) * n_ + nrow) * G_ + g] = fmaxf(acc[mf][nf][r] + gb, 0.f);
            }
        }
}

// ---------------- K6: hpart[ks,p,b,r] = sum_{k in slice} r0_w[p,r,k]*y2flat[b,p,k] ----------------
// 32 slices of 512 k. Block: 64 rows x 32 b x 512 k. Thread: 8 rows x 4 b x k-quad lane.
// Lanes t&3 read contiguous 64B per row -> no over-fetch.
__global__ __launch_bounds__(256, 4) void k_h1(const float* __restrict__ r0w,
                                               const float* __restrict__ y2,
                                               float* __restrict__ hpart) {
    const int ks = blockIdx.x;   // 0..31 (512 k each)
    const int rt = blockIdx.y;   // 0..3  (64 rows each)
    const int p  = blockIdx.z;
    const int t = threadIdx.x;
    const int kq4 = t & 3;          // k-quad lane
    const int bq  = (t >> 2) & 7;   // 8 groups x 4 b
    const int rp  = t >> 5;         // 8 groups x 8 rows
    __shared__ float yl[128 * 36];  // [k][b], pad 36
    const int kc = ks * 512;
    const int row0 = rt * 64 + rp * 8;

    float acc[8][4];
#pragma unroll
    for (int i = 0; i < 8; i++)
#pragma unroll
        for (int j = 0; j < 4; j++) acc[i][j] = 0.f;

    const float* r0base = r0w + ((size_t)(p * R_) + row0) * 16384 + kc;

    for (int sub = 0; sub < 4; sub++) {
        __syncthreads();
        for (int idx = t; idx < 4096; idx += 256) {
            int bb = idx >> 7, kk = idx & 127;
            yl[kk * 36 + bb] = y2[(size_t)(bb * P_ + p) * 16384 + kc + sub * 128 + kk];
        }
        __syncthreads();
        const float* r0s = r0base + sub * 128;
#pragma unroll 2
        for (int it = 0; it < 8; it++) {
            const int kl = it * 16 + kq4 * 4;
            float4 a[8];
#pragma unroll
            for (int i = 0; i < 8; i++)
                a[i] = *reinterpret_cast<const float4*>(r0s + (size_t)i * 16384 + kl);
#pragma unroll
            for (int qq = 0; qq < 4; qq++) {
                const int k = kl + qq;
                float4 yv = *reinterpret_cast<const float4*>(yl + k * 36 + bq * 4);
#pragma unroll
                for (int i = 0; i < 8; i++) {
                    float av = reinterpret_cast<const float*>(&a[i])[qq];
                    acc[i][0] += av * yv.x;
                    acc[i][1] += av * yv.y;
                    acc[i][2] += av * yv.z;
                    acc[i][3] += av * yv.w;
                }
            }
        }
    }
    // reduce over the 4 k-quad lanes (xor 1, 2)
#pragma unroll
    for (int i = 0; i < 8; i++)
#pragma unroll
        for (int j = 0; j < 4; j++) {
            float v = acc[i][j];
            v += __shfl_xor(v, 1);
            v += __shfl_xor(v, 2);
            acc[i][j] = v;
        }
    if (kq4 == 0) {
        // hpart[ks][p][b][r]
#pragma unroll
        for (int j = 0; j < 4; j++) {
            int b = bq * 4 + j;
            float* dst = hpart + (((size_t)(ks * P_ + p) * 32 + b) * 256 + row0);
#pragma unroll
            for (int i = 0; i < 8; i++) dst[i] = acc[i][j];
        }
    }
}

// ---------------- K7: h -> leaky -> w -> res ----------------
__global__ __launch_bounds__(128) void k_wres(const float* __restrict__ hpart,
                                              const float* __restrict__ r1w,
                                              const float* __restrict__ r1b,
                                              const float* __restrict__ r2w,
                                              const float* __restrict__ cap,
                                              const float* __restrict__ tin,
                                              const float* __restrict__ r3w,
                                              const float* __restrict__ r3b,
                                              const float* __restrict__ y2,
                                              float* __restrict__ res) {
    const int p = blockIdx.x, b = blockIdx.y;
    const int t = threadIdx.x;
    __shared__ float lh[256];
    __shared__ float wl[128];
    for (int rr = t; rr < 256; rr += 128) {
        float s = 0.f;
        for (int ks = 0; ks < 32; ks++)
            s += hpart[(((size_t)(ks * P_ + p) * 32 + b) * 256) + rr];
        for (int tt = 0; tt < T_; tt++) s += r1w[(size_t)(p * R_ + rr) * T_ + tt] * tin[b * T_ + tt];
        s += r1b[p * R_ + rr];
        for (int nn = 0; nn < n_; nn++) s += r2w[(size_t)(p * R_ + rr) * n_ + nn] * cap[p * n_ + nn];
        lh[rr] = leakyf(s, 0.01f);
    }
    __syncthreads();
    {
        const int nn = t;
        float accw = r3b[p * n_ + nn];
        const float* r3p = r3w + (size_t)(p * n_ + nn) * R_;
        for (int r = 0; r < 256; r += 4) {
            float4 rv = *reinterpret_cast<const float4*>(r3p + r);
            accw += rv.x * lh[r] + rv.y * lh[r + 1] + rv.z * lh[r + 2] + rv.w * lh[r + 3];
        }
        wl[nn] = fmaxf(accw, 0.f);
    }
    __syncthreads();
    {
        const int g = t;
        float a = 0.f;
        for (int nn = 0; nn < n_; nn++) a += wl[nn] * y2[((size_t)(b * P_ + p) * n_ + nn) * G_ + g];
        res[(b * P_ + p) * G_ + g] = a;
    }
}

// ---------------- K8: out[b,l] ----------------
__global__ __launch_bounds__(128) void k_out(const float* __restrict__ convw,
                                             const float* __restrict__ convb,
                                             const float* __restrict__ res,
                                             float* __restrict__ out) {
    const int b = blockIdx.x;
    const int t = threadIdx.x;
    __shared__ float rl[1024];
    for (int idx = t; idx < 1024; idx += 128) rl[idx] = res[b * 1024 + idx];
    __syncthreads();
    float a = convb[t];
    const float* cw = convw + (size_t)t * 1024;
    for (int gp = 0; gp < 1024; gp += 4) {
        float4 v = *reinterpret_cast<const float4*>(cw + gp);
        a += v.x * rl[((gp + 0) & 7) * 128 + ((gp + 0) >> 3)];
        a += v.y * rl[((gp + 1) & 7) * 128 + ((gp + 1) >> 3)];
        a += v.z * rl[((gp + 2) & 7) * 128 + ((gp + 2) >> 3)];
        a += v.w * rl[((gp + 3) & 7) * 128 + ((gp + 3) >> 3)];
    }
    out[b * L2_ + t] = leakyf(a, 0.02f);
}

extern "C" void kernel_launch(void* const* d_in, const int* in_sizes, int n_in,
                              void* d_out, int out_size, void* d_ws, size_t ws_size,
                              hipStream_t stream) {
    const float* x    = (const float*)d_in[0];
    const float* tin  = (const float*)d_in[1];
    const float* ef   = (const float*)d_in[2];
    const float* linc = (const float*)d_in[3];
    const float* rinc = (const float*)d_in[4];
    const float* cap  = (const float*)d_in[5];
    const float* k1w  = (const float*)d_in[6];
    const float* k1b  = (const float*)d_in[7];
    const float* k2w  = (const float*)d_in[8];
    const float* k3w  = (const float*)d_in[9];
    const float* k4w  = (const float*)d_in[10];
    const float* k5w  = (const float*)d_in[11];
    const float* k5b  = (const float*)d_in[12];
    const float* gcw  = (const float*)d_in[13];
    const float* gcb  = (const float*)d_in[14];
    const float* r0w  = (const float*)d_in[15];
    const float* r1w  = (const float*)d_in[16];
    const float* r1b  = (const float*)d_in[17];
    const float* r2w  = (const float*)d_in[18];
    const float* r3w  = (const float*)d_in[19];
    const float* r3b  = (const float*)d_in[20];
    const float* convw = (const float*)d_in[21];
    const float* convb = (const float*)d_in[22];
    const int* nodes  = (const int*)d_in[23];
    const int* nbr    = (const int*)d_in[24];
    float* out = (float*)d_out;

    float* ws = (float*)d_ws;
    u16*   rxbf   = (u16*)ws;                  // [0, 8388608) f-slots
    u16*   uTbf   = (u16*)(ws + 8388608);      // [8388608, 10485760)
    float* kernb  = ws + 10485760;             // [10485760, 12582912)
    u16*   Qbf    = (u16*)(ws + 12582912);     // [12582912, 29360128)
    float* y2b    = ws + 29360128;             // [29360128, 33554432)
    u16*   lincbf = (u16*)(ws + 33554432);     // 524288 slots
    u16*   lincT  = (u16*)(ws + 34078720);     // 524288
    u16*   rincbf = (u16*)(ws + 34603008);     // 1048576
    u16*   gcwbf  = (u16*)(ws + 35651584);     // 262144
    u16*   Bwbf   = (u16*)(ws + 35913728);     // 65536
    u16*   efbf   = (u16*)(ws + 35979264);     // 32768
    u16*   k5wbf  = (u16*)(ws + 36012032);     // 8192
    float* hpart  = ws;                        // 2,097,152 floats: aliases rx region (dead after k_q)
    float* resb   = ws + 10485760;             // aliases kernb (dead after k_q)

    k_prep <<<3584, 256, 0, stream>>>(linc, rinc, gcw, lincbf, rincbf, gcwbf);
    k_prep2<<<108, 256, 0, stream>>>(linc, k4w, k1w, k2w, k1b, ef, k5w, lincT, Bwbf, efbf, k5wbf);
    k_rx  <<<dim3(8, P_, B_), 256, 0, stream>>>(x, rincbf, nbr, rxbf);
    k_u   <<<dim3(P_, B_),    256, 0, stream>>>(x, k3w, nodes, uTbf);
    k_kern<<<dim3(8, P_, B_), 256, 0, stream>>>(lincT, uTbf, rxbf, Bwbf, efbf, tin, k5wbf, k5b, kernb);
    k_q   <<<dim3(8, P_, B_), 256, 0, stream>>>(rxbf, kernb, gcwbf, Qbf);
    k_y2  <<<dim3(P_, B_),    256, 0, stream>>>(lincbf, Qbf, gcb, y2b);
    k_h1  <<<dim3(32, 4, P_), 256, 0, stream>>>(r0w, y2b, hpart);
    k_wres<<<dim3(P_, B_),    128, 0, stream>>>(hpart, r1w, r1b, r2w, cap, tin, r3w, r3b, y2b, resb);
    k_out <<<B_, 128, 0, stream>>>(convw, convb, resb, out);
}